// Round 7
// baseline (115.927 us; speedup 1.0000x reference)
//
#include <hip/hip_runtime.h>
#include <math.h>

// ---- problem constants ----
#define TT   5
#define CAM  4
#define TC   20
#define BB   2
#define CF   32
#define HC   30
#define WC   40
#define MM   1200
#define NMAX 19
#define EPSF 1e-12f
#define EPS2 1e-24f   // eps^2: 1/max(sqrt(p),EPSF) == rsqrt(max(p,EPS2))
#define JT   75      // 16-col tiles per item
#define RG   38      // row-groups of 32 rows per slot
#define JSP  3       // j-loop split factor (25 tiles each)
#define JQ   25
#define CT   5       // corr/fin tiles of 256 rows

typedef __attribute__((ext_vector_type(8))) short short8v;   // 8 bf16 (4 VGPR)
typedef __attribute__((ext_vector_type(4))) float float4v;

__device__ inline unsigned short f2bf(float x) {
  unsigned int u = __float_as_uint(x);
  unsigned int r = (u + 0x7FFFu + ((u >> 16) & 1u)) >> 16;  // RNE
  return (unsigned short)r;
}
__device__ inline float bf2f(unsigned short h) {
  return __uint_as_float(((unsigned int)h) << 16);
}

__device__ inline void rodrigues_d(const double rv[3], double R[9]) {
  double th = sqrt(rv[0]*rv[0] + rv[1]*rv[1] + rv[2]*rv[2]);
  double thc = fmax(th, 1e-12);
  double kx = rv[0] / thc, ky = rv[1] / thc, kz = rv[2] / thc;
  double st = sin(th), ct = cos(th);
  double Km[9] = { 0.0, -kz,  ky,  kz, 0.0, -kx,  -ky, kx, 0.0 };
  double K2[9];
  for (int r = 0; r < 3; ++r)
    for (int c = 0; c < 3; ++c)
      K2[r*3+c] = Km[r*3+0]*Km[0*3+c] + Km[r*3+1]*Km[1*3+c] + Km[r*3+2]*Km[2*3+c];
  for (int r = 0; r < 3; ++r)
    for (int c = 0; c < 3; ++c)
      R[r*3+c] = (r == c ? 1.0 : 0.0) + st * Km[r*3+c] + (1.0 - ct) * K2[r*3+c];
}
__device__ inline void mm3(const double* A, const double* B, double* C) {
  for (int r = 0; r < 3; ++r)
    for (int c = 0; c < 3; ++c)
      C[r*3+c] = A[r*3+0]*B[0*3+c] + A[r*3+1]*B[1*3+c] + A[r*3+2]*B[2*3+c];
}

__device__ inline bool decode_slot(int slot, const int* ivl, int& n, int& b, int& iv) {
  int ivi = slot / (NMAX * BB);
  int rem = slot % (NMAX * BB);
  n = rem / BB; b = rem % BB;
  iv = ivl[ivi];
  return n < TC - iv;
}

// ------------------------------------------------------------------
// K1 (fused): split role (blocks 0..TC*BB*5-1) + warp role (rest).
// split: channel-L2-normalize, bf16 round, MFMA-ready layout
//        dsp[tcb][kq][pix] (16B per 8 channels).
// warp:  homography (f64) + warped coords per slot.
// ------------------------------------------------------------------
__global__ void k_prep(const float* __restrict__ pred, short8v* __restrict__ dsp,
                       const float* __restrict__ rv_, const float* __restrict__ tv_,
                       const float* __restrict__ nts_, const float* __restrict__ dep_,
                       const float* __restrict__ Ks_, const float* __restrict__ Kin_,
                       const float* __restrict__ osz_, const int* __restrict__ ivl,
                       float2* __restrict__ warped) {
  int bx = blockIdx.x;
  int tid = threadIdx.x;
  if (bx < TC * BB * 5) {
    int tb = bx / 5;
    int pix = (bx % 5) * 240 + tid;
    if (tid >= 240 || pix >= MM) return;
    const float* src = pred + (size_t)tb * CF * MM;
    short8v*     dst = dsp  + (size_t)tb * 4 * MM;
    float v[CF]; float ss = 0.f;
#pragma unroll
    for (int c = 0; c < CF; ++c) { float x = src[c * MM + pix]; v[c] = x; ss = fmaf(x, x, ss); }
    float inv = 1.f / fmaxf(sqrtf(ss), EPSF);
#pragma unroll
    for (int s = 0; s < 4; ++s) {
      short8v oh;
#pragma unroll
      for (int e = 0; e < 8; ++e) oh[e] = (short)f2bf(v[s*8+e] * inv);
      dst[(size_t)s * MM + pix] = oh;
    }
    return;
  }
  // ---- warp role ----
  int slot = bx - TC * BB * 5;
  int n, b, iv;
  if (!decode_slot(slot, ivl, n, b, iv)) return;
  int q0 = n, q1 = n + iv;
  int t0 = q0 / CAM, c0 = q0 % CAM;
  int t1 = q1 / CAM, c1 = q1 % CAM;
  size_t e0 = (size_t)(t0 * BB + b) * CAM + c0;
  size_t e1 = (size_t)(t1 * BB + b) * CAM + c1;

  double rv0[3], tv0[3], rv1[3], tv1[3], nv[3];
  for (int k = 0; k < 3; ++k) {
    rv0[k] = rv_[e0*3 + k]; tv0[k] = tv_[e0*3 + k];
    rv1[k] = rv_[e1*3 + k]; tv1[k] = tv_[e1*3 + k];
    nv[k]  = nts_[e0*3 + k];
  }
  double d = dep_[e0];
  double K9[9], Ki9[9];
  for (int k = 0; k < 9; ++k) { K9[k] = Ks_[e0*9 + k]; Ki9[k] = Kin_[e0*9 + k]; }

  double R0[9], R1[9], R[9];
  rodrigues_d(rv0, R0);
  rodrigues_d(rv1, R1);
  for (int r = 0; r < 3; ++r)
    for (int c = 0; c < 3; ++c)
      R[r*3+c] = R1[r*3+0]*R0[c*3+0] + R1[r*3+1]*R0[c*3+1] + R1[r*3+2]*R0[c*3+2];
  double tvec[3];
  for (int r = 0; r < 3; ++r)
    tvec[r] = tv1[r] - (R[r*3+0]*tv0[0] + R[r*3+1]*tv0[1] + R[r*3+2]*tv0[2]);
  double Mid[9];
  for (int r = 0; r < 3; ++r)
    for (int c = 0; c < 3; ++c)
      Mid[r*3+c] = R[r*3+c] - tvec[r] * nv[c] / d;
  double T1[9], Hm[9];
  mm3(K9, Mid, T1);
  mm3(T1, Ki9, Hm);

  double osz0 = osz_[e0*2 + 0], osz1 = osz_[e0*2 + 1];
  double s0 = 240.0 / osz0, s1 = 320.0 / osz1;
  double sv[3] = { s1, s0, 1.0 };
  double Hs[9];
  for (int r = 0; r < 3; ++r)
    for (int c = 0; c < 3; ++c)
      Hs[r*3+c] = Hm[r*3+c] * sv[r] / sv[c];

  float2* wout = warped + (size_t)slot * MM;
  for (int cell = tid; cell < MM; cell += blockDim.x) {
    double x = (double)((cell % WC) * 8);
    double y = (double)((cell / WC) * 8);
    double wx = Hs[0]*x + Hs[1]*y + Hs[2];
    double wy = Hs[3]*x + Hs[4]*y + Hs[5];
    double wz = Hs[6]*x + Hs[7]*y + Hs[8];
    float z = (float)wz;
    if (fabsf(z) < 1e-8f) z = 1e-8f;
    wout[cell] = make_float2((float)wx / z, (float)wy / z);
  }
}

__device__ inline float4v s_tile1(short8v ah, short8v bh) {
  float4v acc = {0.f, 0.f, 0.f, 0.f};
  return __builtin_amdgcn_mfma_f32_16x16x32_bf16(ah, bh, acc, 0, 0, 0);
}

// inline inverse-norm from JSP partials
__device__ inline float inv_norm3(const float* p, int i) {
  float s = p[i] + p[MM + i] + p[2 * MM + i];
  return rsqrtf(fmaxf(s, EPS2));
}

// ------------------------------------------------------------------
// K3: partial row sum-of-squares. wave = 32 rows (2 tiles), third of
// the j range. Prefetch depth 2.  C/D: col=lane&15, row=(lane>>4)*4+reg.
// ------------------------------------------------------------------
__global__ void __launch_bounds__(64) k_rnorm_p(const short8v* __restrict__ dsp,
                                                const int* __restrict__ ivl,
                                                float* __restrict__ prn) {
  int slot = blockIdx.x, rg = blockIdx.y, jh = blockIdx.z;
  int n, b, iv;
  if (!decode_slot(slot, ivl, n, b, iv)) return;
  int lane = threadIdx.x & 63, q = lane >> 4, li = lane & 15;
  int base = rg * 32;
  bool v1 = (base + 16) < MM;
  int r16a = base, r16b = v1 ? base + 16 : base;
  const short8v* D0 = dsp + (size_t)(n * BB + b) * 4 * MM;
  const short8v* B0 = dsp + (size_t)((n + iv) * BB + b) * 4 * MM + (size_t)q * MM + li;
  short8v ah0 = D0[(size_t)q * MM + r16a + li];
  short8v ah1 = D0[(size_t)q * MM + r16b + li];
  int jt0 = jh * JQ, jtN = jt0 + JQ;
  short8v bA = B0[jt0 * 16];
  short8v bB = B0[min(jt0 + 1, JT - 1) * 16];
  float4v racc0 = {0.f, 0.f, 0.f, 0.f};
  float4v racc1 = {0.f, 0.f, 0.f, 0.f};
#pragma unroll 5
  for (int jt = jt0; jt < jtN; ++jt) {
    short8v bC = B0[min(jt + 2, JT - 1) * 16];
    float4v acc0 = s_tile1(ah0, bA);
    float4v acc1 = s_tile1(ah1, bA);
#pragma unroll
    for (int r = 0; r < 4; ++r) {
      float t0 = fmaxf(acc0[r], 0.f); racc0[r] = fmaf(t0, t0, racc0[r]);
      float t1 = fmaxf(acc1[r], 0.f); racc1[r] = fmaf(t1, t1, racc1[r]);
    }
    bA = bB; bB = bC;
  }
#pragma unroll
  for (int m = 1; m <= 8; m <<= 1)
#pragma unroll
    for (int r = 0; r < 4; ++r) {
      racc0[r] += __shfl_xor(racc0[r], m);
      racc1[r] += __shfl_xor(racc1[r], m);
    }
  if (li == 0) {
    float* o = prn + ((size_t)slot * JSP + jh) * MM;
#pragma unroll
    for (int r = 0; r < 4; ++r) o[r16a + q * 4 + r] = racc0[r];
    if (v1) {
#pragma unroll
      for (int r = 0; r < 4; ++r) o[r16b + q * 4 + r] = racc1[r];
    }
  }
}

// ------------------------------------------------------------------
// K4: partial col sum-of-squares of (relu(S)·irn_i); irn inlined from prn.
// ------------------------------------------------------------------
__global__ void __launch_bounds__(64) k_cnorm_p(const short8v* __restrict__ dsp,
                                                const int* __restrict__ ivl,
                                                const float* __restrict__ prn,
                                                float* __restrict__ pcn) {
  int slot = blockIdx.x, rg = blockIdx.y, jh = blockIdx.z;
  int n, b, iv;
  if (!decode_slot(slot, ivl, n, b, iv)) return;
  int lane = threadIdx.x & 63, q = lane >> 4, li = lane & 15;
  int base = rg * 32;
  bool v1 = (base + 16) < MM;
  int c16a = base, c16b = v1 ? base + 16 : base;
  const short8v* D1 = dsp + (size_t)((n + iv) * BB + b) * 4 * MM;
  const short8v* B0 = dsp + (size_t)(n * BB + b) * 4 * MM + (size_t)q * MM + li;
  short8v ah0 = D1[(size_t)q * MM + c16a + li];
  short8v ah1 = D1[(size_t)q * MM + c16b + li];
  const float* prnS = prn + (size_t)slot * JSP * MM;
  int jt0 = jh * JQ, jtN = jt0 + JQ;
  short8v bA = B0[jt0 * 16];
  short8v bB = B0[min(jt0 + 1, JT - 1) * 16];
  float irA = inv_norm3(prnS, jt0 * 16 + li);
  float irB = inv_norm3(prnS, min(jt0 + 1, JT - 1) * 16 + li);
  float4v cacc0 = {0.f, 0.f, 0.f, 0.f};
  float4v cacc1 = {0.f, 0.f, 0.f, 0.f};
#pragma unroll 5
  for (int jt = jt0; jt < jtN; ++jt) {
    short8v bC = B0[min(jt + 2, JT - 1) * 16];
    float irC = inv_norm3(prnS, min(jt + 2, JT - 1) * 16 + li);
    float4v acc0 = s_tile1(ah0, bA);
    float4v acc1 = s_tile1(ah1, bA);
#pragma unroll
    for (int r = 0; r < 4; ++r) {
      float t0 = fmaxf(acc0[r], 0.f) * irA; cacc0[r] = fmaf(t0, t0, cacc0[r]);
      float t1 = fmaxf(acc1[r], 0.f) * irA; cacc1[r] = fmaf(t1, t1, cacc1[r]);
    }
    bA = bB; bB = bC; irA = irB; irB = irC;
  }
#pragma unroll
  for (int m = 1; m <= 8; m <<= 1)
#pragma unroll
    for (int r = 0; r < 4; ++r) {
      cacc0[r] += __shfl_xor(cacc0[r], m);
      cacc1[r] += __shfl_xor(cacc1[r], m);
    }
  if (li == 0) {
    float* o = pcn + ((size_t)slot * JSP + jh) * MM;
#pragma unroll
    for (int r = 0; r < 4; ++r) o[c16a + q * 4 + r] = cacc0[r];
    if (v1) {
#pragma unroll
      for (int r = 0; r < 4; ++r) o[c16b + q * 4 + r] = cacc1[r];
    }
  }
}

// ------------------------------------------------------------------
// K5: loss, mask-free hot loop; irn/icn inlined from partials.
// ------------------------------------------------------------------
__global__ void __launch_bounds__(64) k_loss(const short8v* __restrict__ dsp,
                                             const int* __restrict__ ivl,
                                             const float* __restrict__ prn,
                                             const float* __restrict__ pcn,
                                             double* __restrict__ partials) {
  int slot = blockIdx.x, rg = blockIdx.y, jh = blockIdx.z;
  int lane = threadIdx.x & 63;
  size_t pidx = ((size_t)slot * RG + rg) * JSP + jh;
  int n, b, iv;
  if (!decode_slot(slot, ivl, n, b, iv)) {
    if (lane == 0) partials[pidx] = 0.0;
    return;
  }
  int q = lane >> 4, li = lane & 15;
  int base = rg * 32;
  bool v1 = (base + 16) < MM;
  int r16a = base, r16b = v1 ? base + 16 : base;
  const short8v* D0 = dsp + (size_t)(n * BB + b) * 4 * MM;
  const short8v* B0 = dsp + (size_t)((n + iv) * BB + b) * 4 * MM + (size_t)q * MM + li;
  short8v ah0 = D0[(size_t)q * MM + r16a + li];
  short8v ah1 = D0[(size_t)q * MM + r16b + li];
  const float* prnS = prn + (size_t)slot * JSP * MM;
  const float* pcnS = pcn + (size_t)slot * JSP * MM;
  float uA[4], uB[4];
#pragma unroll
  for (int r = 0; r < 4; ++r) {
    uA[r] = inv_norm3(prnS, r16a + q * 4 + r);
    uB[r] = v1 ? inv_norm3(prnS, r16b + q * 4 + r) : 0.f;
  }
  int jt0 = jh * JQ, jtN = jt0 + JQ;
  short8v bA = B0[jt0 * 16];
  short8v bB = B0[min(jt0 + 1, JT - 1) * 16];
  float icA = inv_norm3(pcnS, jt0 * 16 + li);
  float icB = inv_norm3(pcnS, min(jt0 + 1, JT - 1) * 16 + li);
  float lacc0 = 0.f, lacc1 = 0.f;
#pragma unroll 5
  for (int jt = jt0; jt < jtN; ++jt) {
    short8v bC = B0[min(jt + 2, JT - 1) * 16];
    float icC = inv_norm3(pcnS, min(jt + 2, JT - 1) * 16 + li);
    float4v acc0 = s_tile1(ah0, bA);
    float4v acc1 = s_tile1(ah1, bA);
#pragma unroll
    for (int r = 0; r < 4; ++r) {
      lacc0 += fmaxf(fmaf(acc0[r], icA * uA[r], -0.2f), 0.f);
      lacc1 += fmaxf(fmaf(acc1[r], icA * uB[r], -0.2f), 0.f);
    }
    bA = bB; bB = bC; icA = icB; icB = icC;
  }
  float lacc = lacc0 + lacc1;
#pragma unroll
  for (int off = 32; off > 0; off >>= 1) lacc += __shfl_xor(lacc, off);
  if (lane == 0) partials[pidx] = (double)lacc;
}

// ------------------------------------------------------------------
// K5b: correction for masked cells (<=4 per row), inlined norms.
// ------------------------------------------------------------------
__global__ void __launch_bounds__(256) k_corr(const short8v* __restrict__ dsp,
                                              const int* __restrict__ ivl,
                                              const float* __restrict__ prn,
                                              const float* __restrict__ pcn,
                                              const float2* __restrict__ warped,
                                              double* __restrict__ partials2) {
  __shared__ double swsum[4];
  int slot = blockIdx.x, tile = blockIdx.y;
  int t = threadIdx.x;
  int n, b, iv;
  bool valid = decode_slot(slot, ivl, n, b, iv);
  double corr = 0.0;
  int row = tile * 256 + t;
  if (valid && row < MM) {
    float2 wp = warped[(size_t)slot * MM + row];
    int kx0 = max(0, (int)ceilf((wp.x - 7.5f) * 0.125f));
    int kx1 = min(WC - 1, (int)floorf((wp.x + 7.5f) * 0.125f));
    int ky0 = max(0, (int)ceilf((wp.y - 7.5f) * 0.125f));
    int ky1 = min(HC - 1, (int)floorf((wp.y + 7.5f) * 0.125f));
    if (kx0 <= kx1 && ky0 <= ky1) {
      const short8v* D0 = dsp + (size_t)(n * BB + b) * 4 * MM;
      const short8v* D1 = dsp + (size_t)((n + iv) * BB + b) * 4 * MM;
      const float* prnS = prn + (size_t)slot * JSP * MM;
      const float* pcnS = pcn + (size_t)slot * JSP * MM;
      float a[CF];
#pragma unroll
      for (int qq = 0; qq < 4; ++qq) {
        short8v h = D0[(size_t)qq * MM + row];
#pragma unroll
        for (int e = 0; e < 8; ++e) a[qq * 8 + e] = bf2f((unsigned short)h[e]);
      }
      float ir = inv_norm3(prnS, row);
      float fcorr = 0.f;
      for (int ky = ky0; ky <= ky1; ++ky) {
        for (int kx = kx0; kx <= kx1; ++kx) {
          float dx = (float)(kx * 8) - wp.x;
          float dy = (float)(ky * 8) - wp.y;
          if (fmaf(dx, dx, dy * dy) <= 56.25f) {
            int j = ky * WC + kx;
            float dot = 0.f;
#pragma unroll
            for (int qq = 0; qq < 4; ++qq) {
              short8v h1 = D1[(size_t)qq * MM + j];
#pragma unroll
              for (int e = 0; e < 8; ++e)
                dot = fmaf(a[qq * 8 + e], bf2f((unsigned short)h1[e]), dot);
            }
            float s = fmaxf(dot, 0.f);
            float D = s * ir * inv_norm3(pcnS, j);
            fcorr += 0.05f * fmaxf(1.f - D, 0.f) - fmaxf(D - 0.2f, 0.f);
          }
        }
      }
      corr = (double)fcorr;
    }
  }
#pragma unroll
  for (int off = 32; off > 0; off >>= 1) corr += __shfl_down(corr, off);
  int wid = t >> 6, lane = t & 63;
  if (lane == 0) swsum[wid] = corr;
  __syncthreads();
  if (t == 0) partials2[(size_t)slot * CT + tile] = swsum[0] + swsum[1] + swsum[2] + swsum[3];
}

// ------------------------------------------------------------------
// K6: final reduction
// ------------------------------------------------------------------
__global__ void k_final(const double* __restrict__ partials,
                        const double* __restrict__ partials2,
                        const int* __restrict__ ivl,
                        int niv, float* __restrict__ out) {
  int lane = threadIdx.x; // 64 threads
  double total = 0.0;
  for (int ivi = 0; ivi < niv; ++ivi) {
    double local = 0.0;
    int base1 = ivi * NMAX * BB * RG * JSP;
    for (int p = lane; p < NMAX * BB * RG * JSP; p += 64) local += partials[base1 + p];
    int base2 = ivi * NMAX * BB * CT;
    for (int p = lane; p < NMAX * BB * CT; p += 64) local += partials2[base2 + p];
    for (int off = 32; off > 0; off >>= 1) local += __shfl_down(local, off);
    int N = TC - ivl[ivi];
    total += local / ((double)N * BB * (double)MM * (double)MM);
  }
  if (lane == 0) out[0] = (float)(total / (double)niv);
}

// ------------------------------------------------------------------
extern "C" void kernel_launch(void* const* d_in, const int* in_sizes, int n_in,
                              void* d_out, int out_size, void* d_ws, size_t ws_size,
                              hipStream_t stream) {
  const float* pred = (const float*)d_in[0];
  const float* rv   = (const float*)d_in[1];
  const float* tv   = (const float*)d_in[2];
  const float* nts  = (const float*)d_in[3];
  const float* dep  = (const float*)d_in[4];
  const float* Ks   = (const float*)d_in[5];
  const float* Kin  = (const float*)d_in[6];
  const float* osz  = (const float*)d_in[7];
  const int*   ivl  = (const int*)d_in[8];
  int niv = in_sizes[8];
  int slots = niv * NMAX * BB;

  char* ws = (char*)d_ws;
  size_t off = 0;
  short8v* dsp = (short8v*)(ws + off);  off += (size_t)TC * BB * 4 * MM * 16;
  float2* warped = (float2*)(ws + off); off += (size_t)slots * MM * 8;
  float* prn = (float*)(ws + off);      off += (size_t)slots * JSP * MM * 4;
  float* pcn = (float*)(ws + off);      off += (size_t)slots * JSP * MM * 4;
  off = (off + 255) & ~(size_t)255;
  double* partials = (double*)(ws + off);  off += (size_t)slots * RG * JSP * 8;
  double* partials2 = (double*)(ws + off); off += (size_t)slots * CT * 8;

  hipLaunchKernelGGL(k_prep, dim3(TC * BB * 5 + slots), dim3(256), 0, stream,
                     pred, dsp, rv, tv, nts, dep, Ks, Kin, osz, ivl, warped);
  dim3 sgrid(slots, RG, JSP);
  dim3 fgrid(slots, CT);
  hipLaunchKernelGGL(k_rnorm_p, sgrid, dim3(64), 0, stream, dsp, ivl, prn);
  hipLaunchKernelGGL(k_cnorm_p, sgrid, dim3(64), 0, stream, dsp, ivl, prn, pcn);
  hipLaunchKernelGGL(k_loss, sgrid, dim3(64), 0, stream, dsp, ivl, prn, pcn, partials);
  hipLaunchKernelGGL(k_corr, fgrid, dim3(256), 0, stream,
                     dsp, ivl, prn, pcn, warped, partials2);
  hipLaunchKernelGGL(k_final, dim3(1), dim3(64), 0, stream,
                     partials, partials2, ivl, niv, (float*)d_out);
}

// Round 8
// 112.620 us; speedup vs baseline: 1.0294x; 1.0294x over previous
//
#include <hip/hip_runtime.h>
#include <math.h>

// ---- problem constants ----
#define TT   5
#define CAM  4
#define TC   20
#define BB   2
#define CF   32
#define HC   30
#define WC   40
#define MM   1200
#define NMAX 19
#define EPSF 1e-12f
#define JT   75      // 16-col tiles per item
#define RG   38      // row-groups of 32 rows per slot
#define RGB  10      // ceil(RG/4) y-blocks (4 waves per block)
#define JSP  3       // j-loop split factor
#define JQ   25      // JT / JSP
#define CT   5       // corr/fin tiles of 256 rows

typedef __attribute__((ext_vector_type(8))) short short8v;   // 8 bf16 (4 VGPR)
typedef __attribute__((ext_vector_type(4))) float float4v;

__device__ inline unsigned short f2bf(float x) {
  unsigned int u = __float_as_uint(x);
  unsigned int r = (u + 0x7FFFu + ((u >> 16) & 1u)) >> 16;  // RNE
  return (unsigned short)r;
}
__device__ inline float bf2f(unsigned short h) {
  return __uint_as_float(((unsigned int)h) << 16);
}

__device__ inline void rodrigues_d(const double rv[3], double R[9]) {
  double th = sqrt(rv[0]*rv[0] + rv[1]*rv[1] + rv[2]*rv[2]);
  double thc = fmax(th, 1e-12);
  double kx = rv[0] / thc, ky = rv[1] / thc, kz = rv[2] / thc;
  double st = sin(th), ct = cos(th);
  double Km[9] = { 0.0, -kz,  ky,  kz, 0.0, -kx,  -ky, kx, 0.0 };
  double K2[9];
  for (int r = 0; r < 3; ++r)
    for (int c = 0; c < 3; ++c)
      K2[r*3+c] = Km[r*3+0]*Km[0*3+c] + Km[r*3+1]*Km[1*3+c] + Km[r*3+2]*Km[2*3+c];
  for (int r = 0; r < 3; ++r)
    for (int c = 0; c < 3; ++c)
      R[r*3+c] = (r == c ? 1.0 : 0.0) + st * Km[r*3+c] + (1.0 - ct) * K2[r*3+c];
}
__device__ inline void mm3(const double* A, const double* B, double* C) {
  for (int r = 0; r < 3; ++r)
    for (int c = 0; c < 3; ++c)
      C[r*3+c] = A[r*3+0]*B[0*3+c] + A[r*3+1]*B[1*3+c] + A[r*3+2]*B[2*3+c];
}

__device__ inline bool decode_slot(int slot, const int* ivl, int& n, int& b, int& iv) {
  int ivi = slot / (NMAX * BB);
  int rem = slot % (NMAX * BB);
  n = rem / BB; b = rem % BB;
  iv = ivl[ivi];
  return n < TC - iv;
}

// ------------------------------------------------------------------
// K1 (fused): split role (blocks 0..TC*BB*5-1) + warp role (rest).
// ------------------------------------------------------------------
__global__ void k_prep(const float* __restrict__ pred, short8v* __restrict__ dsp,
                       const float* __restrict__ rv_, const float* __restrict__ tv_,
                       const float* __restrict__ nts_, const float* __restrict__ dep_,
                       const float* __restrict__ Ks_, const float* __restrict__ Kin_,
                       const float* __restrict__ osz_, const int* __restrict__ ivl,
                       float2* __restrict__ warped) {
  int bx = blockIdx.x;
  int tid = threadIdx.x;
  if (bx < TC * BB * 5) {
    int tb = bx / 5;
    int pix = (bx % 5) * 240 + tid;
    if (tid >= 240 || pix >= MM) return;
    const float* src = pred + (size_t)tb * CF * MM;
    short8v*     dst = dsp  + (size_t)tb * 4 * MM;
    float v[CF]; float ss = 0.f;
#pragma unroll
    for (int c = 0; c < CF; ++c) { float x = src[c * MM + pix]; v[c] = x; ss = fmaf(x, x, ss); }
    float inv = 1.f / fmaxf(sqrtf(ss), EPSF);
#pragma unroll
    for (int s = 0; s < 4; ++s) {
      short8v oh;
#pragma unroll
      for (int e = 0; e < 8; ++e) oh[e] = (short)f2bf(v[s*8+e] * inv);
      dst[(size_t)s * MM + pix] = oh;
    }
    return;
  }
  // ---- warp role ----
  int slot = bx - TC * BB * 5;
  int n, b, iv;
  if (!decode_slot(slot, ivl, n, b, iv)) return;
  int q0 = n, q1 = n + iv;
  int t0 = q0 / CAM, c0 = q0 % CAM;
  int t1 = q1 / CAM, c1 = q1 % CAM;
  size_t e0 = (size_t)(t0 * BB + b) * CAM + c0;
  size_t e1 = (size_t)(t1 * BB + b) * CAM + c1;

  double rv0[3], tv0[3], rv1[3], tv1[3], nv[3];
  for (int k = 0; k < 3; ++k) {
    rv0[k] = rv_[e0*3 + k]; tv0[k] = tv_[e0*3 + k];
    rv1[k] = rv_[e1*3 + k]; tv1[k] = tv_[e1*3 + k];
    nv[k]  = nts_[e0*3 + k];
  }
  double d = dep_[e0];
  double K9[9], Ki9[9];
  for (int k = 0; k < 9; ++k) { K9[k] = Ks_[e0*9 + k]; Ki9[k] = Kin_[e0*9 + k]; }

  double R0[9], R1[9], R[9];
  rodrigues_d(rv0, R0);
  rodrigues_d(rv1, R1);
  for (int r = 0; r < 3; ++r)
    for (int c = 0; c < 3; ++c)
      R[r*3+c] = R1[r*3+0]*R0[c*3+0] + R1[r*3+1]*R0[c*3+1] + R1[r*3+2]*R0[c*3+2];
  double tvec[3];
  for (int r = 0; r < 3; ++r)
    tvec[r] = tv1[r] - (R[r*3+0]*tv0[0] + R[r*3+1]*tv0[1] + R[r*3+2]*tv0[2]);
  double Mid[9];
  for (int r = 0; r < 3; ++r)
    for (int c = 0; c < 3; ++c)
      Mid[r*3+c] = R[r*3+c] - tvec[r] * nv[c] / d;
  double T1[9], Hm[9];
  mm3(K9, Mid, T1);
  mm3(T1, Ki9, Hm);

  double osz0 = osz_[e0*2 + 0], osz1 = osz_[e0*2 + 1];
  double s0 = 240.0 / osz0, s1 = 320.0 / osz1;
  double sv[3] = { s1, s0, 1.0 };
  double Hs[9];
  for (int r = 0; r < 3; ++r)
    for (int c = 0; c < 3; ++c)
      Hs[r*3+c] = Hm[r*3+c] * sv[r] / sv[c];

  float2* wout = warped + (size_t)slot * MM;
  for (int cell = tid; cell < MM; cell += blockDim.x) {
    double x = (double)((cell % WC) * 8);
    double y = (double)((cell / WC) * 8);
    double wx = Hs[0]*x + Hs[1]*y + Hs[2];
    double wy = Hs[3]*x + Hs[4]*y + Hs[5];
    double wz = Hs[6]*x + Hs[7]*y + Hs[8];
    float z = (float)wz;
    if (fabsf(z) < 1e-8f) z = 1e-8f;
    wout[cell] = make_float2((float)wx / z, (float)wy / z);
  }
}

__device__ inline float4v s_tile1(short8v ah, short8v bh) {
  float4v acc = {0.f, 0.f, 0.f, 0.f};
  return __builtin_amdgcn_mfma_f32_16x16x32_bf16(ah, bh, acc, 0, 0, 0);
}

// ------------------------------------------------------------------
// K3: partial row sum-of-squares. 4 independent waves/block (no
// barriers); wave -> rowgroup rg = blockIdx.y*4 + wid (32 rows each);
// blockIdx.z = third of the j range. Prefetch depth 2.
// C/D: col=lane&15, row=(lane>>4)*4+reg.
// ------------------------------------------------------------------
__global__ void __launch_bounds__(256) k_rnorm_p(const short8v* __restrict__ dsp,
                                                 const int* __restrict__ ivl,
                                                 float* __restrict__ prn) {
  int slot = blockIdx.x, jh = blockIdx.z;
  int n, b, iv;
  if (!decode_slot(slot, ivl, n, b, iv)) return;
  int wid = threadIdx.x >> 6, lane = threadIdx.x & 63;
  int rg = blockIdx.y * 4 + wid;
  if (rg >= RG) return;
  int q = lane >> 4, li = lane & 15;
  int base = rg * 32;
  bool v1 = (base + 16) < MM;
  int r16a = base, r16b = v1 ? base + 16 : base;
  const short8v* D0 = dsp + (size_t)(n * BB + b) * 4 * MM;
  const short8v* B0 = dsp + (size_t)((n + iv) * BB + b) * 4 * MM + (size_t)q * MM + li;
  short8v ah0 = D0[(size_t)q * MM + r16a + li];
  short8v ah1 = D0[(size_t)q * MM + r16b + li];
  int jt0 = jh * JQ, jtN = jt0 + JQ;
  short8v bA = B0[jt0 * 16];
  short8v bB = B0[min(jt0 + 1, JT - 1) * 16];
  float4v racc0 = {0.f, 0.f, 0.f, 0.f};
  float4v racc1 = {0.f, 0.f, 0.f, 0.f};
#pragma unroll 5
  for (int jt = jt0; jt < jtN; ++jt) {
    short8v bC = B0[min(jt + 2, JT - 1) * 16];
    float4v acc0 = s_tile1(ah0, bA);
    float4v acc1 = s_tile1(ah1, bA);
#pragma unroll
    for (int r = 0; r < 4; ++r) {
      float t0 = fmaxf(acc0[r], 0.f); racc0[r] = fmaf(t0, t0, racc0[r]);
      float t1 = fmaxf(acc1[r], 0.f); racc1[r] = fmaf(t1, t1, racc1[r]);
    }
    bA = bB; bB = bC;
  }
#pragma unroll
  for (int m = 1; m <= 8; m <<= 1)
#pragma unroll
    for (int r = 0; r < 4; ++r) {
      racc0[r] += __shfl_xor(racc0[r], m);
      racc1[r] += __shfl_xor(racc1[r], m);
    }
  if (li == 0) {
    float* o = prn + ((size_t)slot * JSP + jh) * MM;
#pragma unroll
    for (int r = 0; r < 4; ++r) o[r16a + q * 4 + r] = racc0[r];
    if (v1) {
#pragma unroll
      for (int r = 0; r < 4; ++r) o[r16b + q * 4 + r] = racc1[r];
    }
  }
}

// K3b: finisher -> irn = 1/max(sqrt(p0+p1+p2), eps)
__global__ void __launch_bounds__(256) k_rnorm_fin(const float* __restrict__ prn,
                                                   const int* __restrict__ ivl,
                                                   float* __restrict__ irn) {
  int slot = blockIdx.x;
  int n, b, iv;
  if (!decode_slot(slot, ivl, n, b, iv)) return;
  int row = blockIdx.y * 256 + threadIdx.x;
  if (row >= MM) return;
  const float* p = prn + (size_t)slot * JSP * MM;
  float s = p[row] + p[MM + row] + p[2 * MM + row];
  irn[(size_t)slot * MM + row] = 1.f / fmaxf(sqrtf(s), EPSF);
}

// ------------------------------------------------------------------
// K4: partial col sum-of-squares of (relu(S)·irn_i). Same structure.
// ------------------------------------------------------------------
__global__ void __launch_bounds__(256) k_cnorm_p(const short8v* __restrict__ dsp,
                                                 const int* __restrict__ ivl,
                                                 const float* __restrict__ irn,
                                                 float* __restrict__ pcn) {
  int slot = blockIdx.x, jh = blockIdx.z;
  int n, b, iv;
  if (!decode_slot(slot, ivl, n, b, iv)) return;
  int wid = threadIdx.x >> 6, lane = threadIdx.x & 63;
  int rg = blockIdx.y * 4 + wid;
  if (rg >= RG) return;
  int q = lane >> 4, li = lane & 15;
  int base = rg * 32;
  bool v1 = (base + 16) < MM;
  int c16a = base, c16b = v1 ? base + 16 : base;
  const short8v* D1 = dsp + (size_t)((n + iv) * BB + b) * 4 * MM;
  const short8v* B0 = dsp + (size_t)(n * BB + b) * 4 * MM + (size_t)q * MM + li;
  short8v ah0 = D1[(size_t)q * MM + c16a + li];
  short8v ah1 = D1[(size_t)q * MM + c16b + li];
  const float* irnS = irn + (size_t)slot * MM + li;
  int jt0 = jh * JQ, jtN = jt0 + JQ;
  short8v bA = B0[jt0 * 16];
  short8v bB = B0[min(jt0 + 1, JT - 1) * 16];
  float irA = irnS[jt0 * 16];
  float irB = irnS[min(jt0 + 1, JT - 1) * 16];
  float4v cacc0 = {0.f, 0.f, 0.f, 0.f};
  float4v cacc1 = {0.f, 0.f, 0.f, 0.f};
#pragma unroll 5
  for (int jt = jt0; jt < jtN; ++jt) {
    short8v bC = B0[min(jt + 2, JT - 1) * 16];
    float irC = irnS[min(jt + 2, JT - 1) * 16];
    float4v acc0 = s_tile1(ah0, bA);
    float4v acc1 = s_tile1(ah1, bA);
#pragma unroll
    for (int r = 0; r < 4; ++r) {
      float t0 = fmaxf(acc0[r], 0.f) * irA; cacc0[r] = fmaf(t0, t0, cacc0[r]);
      float t1 = fmaxf(acc1[r], 0.f) * irA; cacc1[r] = fmaf(t1, t1, cacc1[r]);
    }
    bA = bB; bB = bC; irA = irB; irB = irC;
  }
#pragma unroll
  for (int m = 1; m <= 8; m <<= 1)
#pragma unroll
    for (int r = 0; r < 4; ++r) {
      cacc0[r] += __shfl_xor(cacc0[r], m);
      cacc1[r] += __shfl_xor(cacc1[r], m);
    }
  if (li == 0) {
    float* o = pcn + ((size_t)slot * JSP + jh) * MM;
#pragma unroll
    for (int r = 0; r < 4; ++r) o[c16a + q * 4 + r] = cacc0[r];
    if (v1) {
#pragma unroll
      for (int r = 0; r < 4; ++r) o[c16b + q * 4 + r] = cacc1[r];
    }
  }
}

// K4b: finisher -> icn
__global__ void __launch_bounds__(256) k_cnorm_fin(const float* __restrict__ pcn,
                                                   const int* __restrict__ ivl,
                                                   float* __restrict__ icn) {
  int slot = blockIdx.x;
  int n, b, iv;
  if (!decode_slot(slot, ivl, n, b, iv)) return;
  int col = blockIdx.y * 256 + threadIdx.x;
  if (col >= MM) return;
  const float* p = pcn + (size_t)slot * JSP * MM;
  float s = p[col] + p[MM + col] + p[2 * MM + col];
  icn[(size_t)slot * MM + col] = 1.f / fmaxf(sqrtf(s), EPSF);
}

// ------------------------------------------------------------------
// K5: loss, mask-free hot loop. Same 4-wave structure.
// ------------------------------------------------------------------
__global__ void __launch_bounds__(256) k_loss(const short8v* __restrict__ dsp,
                                              const int* __restrict__ ivl,
                                              const float* __restrict__ irn,
                                              const float* __restrict__ icn,
                                              double* __restrict__ partials) {
  int slot = blockIdx.x, jh = blockIdx.z;
  int wid = threadIdx.x >> 6, lane = threadIdx.x & 63;
  int rg = blockIdx.y * 4 + wid;
  if (rg >= RG) return;
  size_t pidx = ((size_t)slot * RG + rg) * JSP + jh;
  int n, b, iv;
  if (!decode_slot(slot, ivl, n, b, iv)) {
    if (lane == 0) partials[pidx] = 0.0;
    return;
  }
  int q = lane >> 4, li = lane & 15;
  int base = rg * 32;
  bool v1 = (base + 16) < MM;
  int r16a = base, r16b = v1 ? base + 16 : base;
  const short8v* D0 = dsp + (size_t)(n * BB + b) * 4 * MM;
  const short8v* B0 = dsp + (size_t)((n + iv) * BB + b) * 4 * MM + (size_t)q * MM + li;
  short8v ah0 = D0[(size_t)q * MM + r16a + li];
  short8v ah1 = D0[(size_t)q * MM + r16b + li];
  float uA[4], uB[4];
#pragma unroll
  for (int r = 0; r < 4; ++r) {
    uA[r] = irn[(size_t)slot * MM + r16a + q * 4 + r];
    uB[r] = v1 ? irn[(size_t)slot * MM + r16b + q * 4 + r] : 0.f;
  }
  const float* icnS = icn + (size_t)slot * MM + li;
  int jt0 = jh * JQ, jtN = jt0 + JQ;
  short8v bA = B0[jt0 * 16];
  short8v bB = B0[min(jt0 + 1, JT - 1) * 16];
  float icA = icnS[jt0 * 16];
  float icB = icnS[min(jt0 + 1, JT - 1) * 16];
  float lacc0 = 0.f, lacc1 = 0.f;
#pragma unroll 5
  for (int jt = jt0; jt < jtN; ++jt) {
    short8v bC = B0[min(jt + 2, JT - 1) * 16];
    float icC = icnS[min(jt + 2, JT - 1) * 16];
    float4v acc0 = s_tile1(ah0, bA);
    float4v acc1 = s_tile1(ah1, bA);
#pragma unroll
    for (int r = 0; r < 4; ++r) {
      lacc0 += fmaxf(fmaf(acc0[r], icA * uA[r], -0.2f), 0.f);
      lacc1 += fmaxf(fmaf(acc1[r], icA * uB[r], -0.2f), 0.f);
    }
    bA = bB; bB = bC; icA = icB; icB = icC;
  }
  float lacc = lacc0 + lacc1;
#pragma unroll
  for (int off = 32; off > 0; off >>= 1) lacc += __shfl_xor(lacc, off);
  if (lane == 0) partials[pidx] = (double)lacc;
}

// ------------------------------------------------------------------
// K5b: correction for masked cells (<=4 per row).
// ------------------------------------------------------------------
__global__ void __launch_bounds__(256) k_corr(const short8v* __restrict__ dsp,
                                              const int* __restrict__ ivl,
                                              const float* __restrict__ irn,
                                              const float* __restrict__ icn,
                                              const float2* __restrict__ warped,
                                              double* __restrict__ partials2) {
  __shared__ double swsum[4];
  int slot = blockIdx.x, tile = blockIdx.y;
  int t = threadIdx.x;
  int n, b, iv;
  bool valid = decode_slot(slot, ivl, n, b, iv);
  double corr = 0.0;
  int row = tile * 256 + t;
  if (valid && row < MM) {
    float2 wp = warped[(size_t)slot * MM + row];
    int kx0 = max(0, (int)ceilf((wp.x - 7.5f) * 0.125f));
    int kx1 = min(WC - 1, (int)floorf((wp.x + 7.5f) * 0.125f));
    int ky0 = max(0, (int)ceilf((wp.y - 7.5f) * 0.125f));
    int ky1 = min(HC - 1, (int)floorf((wp.y + 7.5f) * 0.125f));
    if (kx0 <= kx1 && ky0 <= ky1) {
      const short8v* D0 = dsp + (size_t)(n * BB + b) * 4 * MM;
      const short8v* D1 = dsp + (size_t)((n + iv) * BB + b) * 4 * MM;
      float a[CF];
#pragma unroll
      for (int qq = 0; qq < 4; ++qq) {
        short8v h = D0[(size_t)qq * MM + row];
#pragma unroll
        for (int e = 0; e < 8; ++e) a[qq * 8 + e] = bf2f((unsigned short)h[e]);
      }
      float ir = irn[(size_t)slot * MM + row];
      float fcorr = 0.f;
      for (int ky = ky0; ky <= ky1; ++ky) {
        for (int kx = kx0; kx <= kx1; ++kx) {
          float dx = (float)(kx * 8) - wp.x;
          float dy = (float)(ky * 8) - wp.y;
          if (fmaf(dx, dx, dy * dy) <= 56.25f) {
            int j = ky * WC + kx;
            float dot = 0.f;
#pragma unroll
            for (int qq = 0; qq < 4; ++qq) {
              short8v h1 = D1[(size_t)qq * MM + j];
#pragma unroll
              for (int e = 0; e < 8; ++e)
                dot = fmaf(a[qq * 8 + e], bf2f((unsigned short)h1[e]), dot);
            }
            float s = fmaxf(dot, 0.f);
            float D = s * ir * icn[(size_t)slot * MM + j];
            fcorr += 0.05f * fmaxf(1.f - D, 0.f) - fmaxf(D - 0.2f, 0.f);
          }
        }
      }
      corr = (double)fcorr;
    }
  }
#pragma unroll
  for (int off = 32; off > 0; off >>= 1) corr += __shfl_down(corr, off);
  int wid = t >> 6, lane = t & 63;
  if (lane == 0) swsum[wid] = corr;
  __syncthreads();
  if (t == 0) partials2[(size_t)slot * CT + tile] = swsum[0] + swsum[1] + swsum[2] + swsum[3];
}

// ------------------------------------------------------------------
// K6: final reduction
// ------------------------------------------------------------------
__global__ void k_final(const double* __restrict__ partials,
                        const double* __restrict__ partials2,
                        const int* __restrict__ ivl,
                        int niv, float* __restrict__ out) {
  int lane = threadIdx.x; // 64 threads
  double total = 0.0;
  for (int ivi = 0; ivi < niv; ++ivi) {
    double local = 0.0;
    int base1 = ivi * NMAX * BB * RG * JSP;
    for (int p = lane; p < NMAX * BB * RG * JSP; p += 64) local += partials[base1 + p];
    int base2 = ivi * NMAX * BB * CT;
    for (int p = lane; p < NMAX * BB * CT; p += 64) local += partials2[base2 + p];
    for (int off = 32; off > 0; off >>= 1) local += __shfl_down(local, off);
    int N = TC - ivl[ivi];
    total += local / ((double)N * BB * (double)MM * (double)MM);
  }
  if (lane == 0) out[0] = (float)(total / (double)niv);
}

// ------------------------------------------------------------------
extern "C" void kernel_launch(void* const* d_in, const int* in_sizes, int n_in,
                              void* d_out, int out_size, void* d_ws, size_t ws_size,
                              hipStream_t stream) {
  const float* pred = (const float*)d_in[0];
  const float* rv   = (const float*)d_in[1];
  const float* tv   = (const float*)d_in[2];
  const float* nts  = (const float*)d_in[3];
  const float* dep  = (const float*)d_in[4];
  const float* Ks   = (const float*)d_in[5];
  const float* Kin  = (const float*)d_in[6];
  const float* osz  = (const float*)d_in[7];
  const int*   ivl  = (const int*)d_in[8];
  int niv = in_sizes[8];
  int slots = niv * NMAX * BB;

  char* ws = (char*)d_ws;
  size_t off = 0;
  short8v* dsp = (short8v*)(ws + off);  off += (size_t)TC * BB * 4 * MM * 16;
  float2* warped = (float2*)(ws + off); off += (size_t)slots * MM * 8;
  float* prn = (float*)(ws + off);      off += (size_t)slots * JSP * MM * 4;
  float* pcn = (float*)(ws + off);      off += (size_t)slots * JSP * MM * 4;
  float* irn = (float*)(ws + off);      off += (size_t)slots * MM * 4;
  float* icn = (float*)(ws + off);      off += (size_t)slots * MM * 4;
  off = (off + 255) & ~(size_t)255;
  double* partials = (double*)(ws + off);  off += (size_t)slots * RG * JSP * 8;
  double* partials2 = (double*)(ws + off); off += (size_t)slots * CT * 8;

  hipLaunchKernelGGL(k_prep, dim3(TC * BB * 5 + slots), dim3(256), 0, stream,
                     pred, dsp, rv, tv, nts, dep, Ks, Kin, osz, ivl, warped);
  dim3 sgrid(slots, RGB, JSP);
  dim3 fgrid(slots, CT);
  hipLaunchKernelGGL(k_rnorm_p, sgrid, dim3(256), 0, stream, dsp, ivl, prn);
  hipLaunchKernelGGL(k_rnorm_fin, fgrid, dim3(256), 0, stream, prn, ivl, irn);
  hipLaunchKernelGGL(k_cnorm_p, sgrid, dim3(256), 0, stream, dsp, ivl, irn, pcn);
  hipLaunchKernelGGL(k_cnorm_fin, fgrid, dim3(256), 0, stream, pcn, ivl, icn);
  hipLaunchKernelGGL(k_loss, sgrid, dim3(256), 0, stream, dsp, ivl, irn, icn, partials);
  hipLaunchKernelGGL(k_corr, fgrid, dim3(256), 0, stream,
                     dsp, ivl, irn, icn, warped, partials2);
  hipLaunchKernelGGL(k_final, dim3(1), dim3(64), 0, stream,
                     partials, partials2, ivl, niv, (float*)d_out);
}

// Round 9
// 80.931 us; speedup vs baseline: 1.4324x; 1.3916x over previous
//
#include <hip/hip_runtime.h>
#include <math.h>

// ---- problem constants ----
#define TT   5
#define CAM  4
#define TC   20
#define BB   2
#define CF   32
#define HC   30
#define WC   40
#define MM   1200
#define NMAX 19
#define EPSF 1e-12f
#define JT   75      // 16-col tiles per item
#define RG   38      // row-groups of 32 rows per slot
#define RGB  10      // ceil(RG/4) y-blocks (4 waves per block)
#define JSP  3       // j-loop split factor
#define JQ   25      // JT / JSP
#define CT   5       // corr tiles of 256 rows
#define REDB 16      // stage-1 reduction blocks

typedef __attribute__((ext_vector_type(8))) short short8v;   // 8 bf16 (4 VGPR)
typedef __attribute__((ext_vector_type(4))) float float4v;

__device__ inline unsigned short f2bf(float x) {
  unsigned int u = __float_as_uint(x);
  unsigned int r = (u + 0x7FFFu + ((u >> 16) & 1u)) >> 16;  // RNE
  return (unsigned short)r;
}
__device__ inline float bf2f(unsigned short h) {
  return __uint_as_float(((unsigned int)h) << 16);
}

__device__ inline void rodrigues_d(const double rv[3], double R[9]) {
  double th = sqrt(rv[0]*rv[0] + rv[1]*rv[1] + rv[2]*rv[2]);
  double thc = fmax(th, 1e-12);
  double kx = rv[0] / thc, ky = rv[1] / thc, kz = rv[2] / thc;
  double st = sin(th), ct = cos(th);
  double Km[9] = { 0.0, -kz,  ky,  kz, 0.0, -kx,  -ky, kx, 0.0 };
  double K2[9];
  for (int r = 0; r < 3; ++r)
    for (int c = 0; c < 3; ++c)
      K2[r*3+c] = Km[r*3+0]*Km[0*3+c] + Km[r*3+1]*Km[1*3+c] + Km[r*3+2]*Km[2*3+c];
  for (int r = 0; r < 3; ++r)
    for (int c = 0; c < 3; ++c)
      R[r*3+c] = (r == c ? 1.0 : 0.0) + st * Km[r*3+c] + (1.0 - ct) * K2[r*3+c];
}
__device__ inline void mm3(const double* A, const double* B, double* C) {
  for (int r = 0; r < 3; ++r)
    for (int c = 0; c < 3; ++c)
      C[r*3+c] = A[r*3+0]*B[0*3+c] + A[r*3+1]*B[1*3+c] + A[r*3+2]*B[2*3+c];
}

__device__ inline bool decode_slot(int slot, const int* ivl, int& n, int& b, int& iv) {
  int ivi = slot / (NMAX * BB);
  int rem = slot % (NMAX * BB);
  n = rem / BB; b = rem % BB;
  iv = ivl[ivi];
  return n < TC - iv;
}

// ------------------------------------------------------------------
// K1 (fused): split role (blocks 0..TC*BB*5-1) + warp role (rest).
// ------------------------------------------------------------------
__global__ void k_prep(const float* __restrict__ pred, short8v* __restrict__ dsp,
                       const float* __restrict__ rv_, const float* __restrict__ tv_,
                       const float* __restrict__ nts_, const float* __restrict__ dep_,
                       const float* __restrict__ Ks_, const float* __restrict__ Kin_,
                       const float* __restrict__ osz_, const int* __restrict__ ivl,
                       float2* __restrict__ warped) {
  int bx = blockIdx.x;
  int tid = threadIdx.x;
  if (bx < TC * BB * 5) {
    int tb = bx / 5;
    int pix = (bx % 5) * 240 + tid;
    if (tid >= 240 || pix >= MM) return;
    const float* src = pred + (size_t)tb * CF * MM;
    short8v*     dst = dsp  + (size_t)tb * 4 * MM;
    float v[CF]; float ss = 0.f;
#pragma unroll
    for (int c = 0; c < CF; ++c) { float x = src[c * MM + pix]; v[c] = x; ss = fmaf(x, x, ss); }
    float inv = 1.f / fmaxf(sqrtf(ss), EPSF);
#pragma unroll
    for (int s = 0; s < 4; ++s) {
      short8v oh;
#pragma unroll
      for (int e = 0; e < 8; ++e) oh[e] = (short)f2bf(v[s*8+e] * inv);
      dst[(size_t)s * MM + pix] = oh;
    }
    return;
  }
  // ---- warp role ----
  int slot = bx - TC * BB * 5;
  int n, b, iv;
  if (!decode_slot(slot, ivl, n, b, iv)) return;
  int q0 = n, q1 = n + iv;
  int t0 = q0 / CAM, c0 = q0 % CAM;
  int t1 = q1 / CAM, c1 = q1 % CAM;
  size_t e0 = (size_t)(t0 * BB + b) * CAM + c0;
  size_t e1 = (size_t)(t1 * BB + b) * CAM + c1;

  double rv0[3], tv0[3], rv1[3], tv1[3], nv[3];
  for (int k = 0; k < 3; ++k) {
    rv0[k] = rv_[e0*3 + k]; tv0[k] = tv_[e0*3 + k];
    rv1[k] = rv_[e1*3 + k]; tv1[k] = tv_[e1*3 + k];
    nv[k]  = nts_[e0*3 + k];
  }
  double d = dep_[e0];
  double K9[9], Ki9[9];
  for (int k = 0; k < 9; ++k) { K9[k] = Ks_[e0*9 + k]; Ki9[k] = Kin_[e0*9 + k]; }

  double R0[9], R1[9], R[9];
  rodrigues_d(rv0, R0);
  rodrigues_d(rv1, R1);
  for (int r = 0; r < 3; ++r)
    for (int c = 0; c < 3; ++c)
      R[r*3+c] = R1[r*3+0]*R0[c*3+0] + R1[r*3+1]*R0[c*3+1] + R1[r*3+2]*R0[c*3+2];
  double tvec[3];
  for (int r = 0; r < 3; ++r)
    tvec[r] = tv1[r] - (R[r*3+0]*tv0[0] + R[r*3+1]*tv0[1] + R[r*3+2]*tv0[2]);
  double Mid[9];
  for (int r = 0; r < 3; ++r)
    for (int c = 0; c < 3; ++c)
      Mid[r*3+c] = R[r*3+c] - tvec[r] * nv[c] / d;
  double T1[9], Hm[9];
  mm3(K9, Mid, T1);
  mm3(T1, Ki9, Hm);

  double osz0 = osz_[e0*2 + 0], osz1 = osz_[e0*2 + 1];
  double s0 = 240.0 / osz0, s1 = 320.0 / osz1;
  double sv[3] = { s1, s0, 1.0 };
  double Hs[9];
  for (int r = 0; r < 3; ++r)
    for (int c = 0; c < 3; ++c)
      Hs[r*3+c] = Hm[r*3+c] * sv[r] / sv[c];

  float2* wout = warped + (size_t)slot * MM;
  for (int cell = tid; cell < MM; cell += blockDim.x) {
    double x = (double)((cell % WC) * 8);
    double y = (double)((cell / WC) * 8);
    double wx = Hs[0]*x + Hs[1]*y + Hs[2];
    double wy = Hs[3]*x + Hs[4]*y + Hs[5];
    double wz = Hs[6]*x + Hs[7]*y + Hs[8];
    float z = (float)wz;
    if (fabsf(z) < 1e-8f) z = 1e-8f;
    wout[cell] = make_float2((float)wx / z, (float)wy / z);
  }
}

__device__ inline float4v s_tile1(short8v ah, short8v bh) {
  float4v acc = {0.f, 0.f, 0.f, 0.f};
  return __builtin_amdgcn_mfma_f32_16x16x32_bf16(ah, bh, acc, 0, 0, 0);
}

// ------------------------------------------------------------------
// K3: partial row sum-of-squares. 4 independent waves/block.
// ------------------------------------------------------------------
__global__ void __launch_bounds__(256) k_rnorm_p(const short8v* __restrict__ dsp,
                                                 const int* __restrict__ ivl,
                                                 float* __restrict__ prn) {
  int slot = blockIdx.x, jh = blockIdx.z;
  int n, b, iv;
  if (!decode_slot(slot, ivl, n, b, iv)) return;
  int wid = threadIdx.x >> 6, lane = threadIdx.x & 63;
  int rg = blockIdx.y * 4 + wid;
  if (rg >= RG) return;
  int q = lane >> 4, li = lane & 15;
  int base = rg * 32;
  bool v1 = (base + 16) < MM;
  int r16a = base, r16b = v1 ? base + 16 : base;
  const short8v* D0 = dsp + (size_t)(n * BB + b) * 4 * MM;
  const short8v* B0 = dsp + (size_t)((n + iv) * BB + b) * 4 * MM + (size_t)q * MM + li;
  short8v ah0 = D0[(size_t)q * MM + r16a + li];
  short8v ah1 = D0[(size_t)q * MM + r16b + li];
  int jt0 = jh * JQ, jtN = jt0 + JQ;
  short8v bA = B0[jt0 * 16];
  short8v bB = B0[min(jt0 + 1, JT - 1) * 16];
  float4v racc0 = {0.f, 0.f, 0.f, 0.f};
  float4v racc1 = {0.f, 0.f, 0.f, 0.f};
#pragma unroll 5
  for (int jt = jt0; jt < jtN; ++jt) {
    short8v bC = B0[min(jt + 2, JT - 1) * 16];
    float4v acc0 = s_tile1(ah0, bA);
    float4v acc1 = s_tile1(ah1, bA);
#pragma unroll
    for (int r = 0; r < 4; ++r) {
      float t0 = fmaxf(acc0[r], 0.f); racc0[r] = fmaf(t0, t0, racc0[r]);
      float t1 = fmaxf(acc1[r], 0.f); racc1[r] = fmaf(t1, t1, racc1[r]);
    }
    bA = bB; bB = bC;
  }
#pragma unroll
  for (int m = 1; m <= 8; m <<= 1)
#pragma unroll
    for (int r = 0; r < 4; ++r) {
      racc0[r] += __shfl_xor(racc0[r], m);
      racc1[r] += __shfl_xor(racc1[r], m);
    }
  if (li == 0) {
    float* o = prn + ((size_t)slot * JSP + jh) * MM;
#pragma unroll
    for (int r = 0; r < 4; ++r) o[r16a + q * 4 + r] = racc0[r];
    if (v1) {
#pragma unroll
      for (int r = 0; r < 4; ++r) o[r16b + q * 4 + r] = racc1[r];
    }
  }
}

// K3b: finisher -> irn
__global__ void __launch_bounds__(256) k_rnorm_fin(const float* __restrict__ prn,
                                                   const int* __restrict__ ivl,
                                                   float* __restrict__ irn) {
  int slot = blockIdx.x;
  int n, b, iv;
  if (!decode_slot(slot, ivl, n, b, iv)) return;
  int row = blockIdx.y * 256 + threadIdx.x;
  if (row >= MM) return;
  const float* p = prn + (size_t)slot * JSP * MM;
  float s = p[row] + p[MM + row] + p[2 * MM + row];
  irn[(size_t)slot * MM + row] = 1.f / fmaxf(sqrtf(s), EPSF);
}

// ------------------------------------------------------------------
// K4: partial col sum-of-squares of (relu(S)·irn_i).
// ------------------------------------------------------------------
__global__ void __launch_bounds__(256) k_cnorm_p(const short8v* __restrict__ dsp,
                                                 const int* __restrict__ ivl,
                                                 const float* __restrict__ irn,
                                                 float* __restrict__ pcn) {
  int slot = blockIdx.x, jh = blockIdx.z;
  int n, b, iv;
  if (!decode_slot(slot, ivl, n, b, iv)) return;
  int wid = threadIdx.x >> 6, lane = threadIdx.x & 63;
  int rg = blockIdx.y * 4 + wid;
  if (rg >= RG) return;
  int q = lane >> 4, li = lane & 15;
  int base = rg * 32;
  bool v1 = (base + 16) < MM;
  int c16a = base, c16b = v1 ? base + 16 : base;
  const short8v* D1 = dsp + (size_t)((n + iv) * BB + b) * 4 * MM;
  const short8v* B0 = dsp + (size_t)(n * BB + b) * 4 * MM + (size_t)q * MM + li;
  short8v ah0 = D1[(size_t)q * MM + c16a + li];
  short8v ah1 = D1[(size_t)q * MM + c16b + li];
  const float* irnS = irn + (size_t)slot * MM + li;
  int jt0 = jh * JQ, jtN = jt0 + JQ;
  short8v bA = B0[jt0 * 16];
  short8v bB = B0[min(jt0 + 1, JT - 1) * 16];
  float irA = irnS[jt0 * 16];
  float irB = irnS[min(jt0 + 1, JT - 1) * 16];
  float4v cacc0 = {0.f, 0.f, 0.f, 0.f};
  float4v cacc1 = {0.f, 0.f, 0.f, 0.f};
#pragma unroll 5
  for (int jt = jt0; jt < jtN; ++jt) {
    short8v bC = B0[min(jt + 2, JT - 1) * 16];
    float irC = irnS[min(jt + 2, JT - 1) * 16];
    float4v acc0 = s_tile1(ah0, bA);
    float4v acc1 = s_tile1(ah1, bA);
#pragma unroll
    for (int r = 0; r < 4; ++r) {
      float t0 = fmaxf(acc0[r], 0.f) * irA; cacc0[r] = fmaf(t0, t0, cacc0[r]);
      float t1 = fmaxf(acc1[r], 0.f) * irA; cacc1[r] = fmaf(t1, t1, cacc1[r]);
    }
    bA = bB; bB = bC; irA = irB; irB = irC;
  }
#pragma unroll
  for (int m = 1; m <= 8; m <<= 1)
#pragma unroll
    for (int r = 0; r < 4; ++r) {
      cacc0[r] += __shfl_xor(cacc0[r], m);
      cacc1[r] += __shfl_xor(cacc1[r], m);
    }
  if (li == 0) {
    float* o = pcn + ((size_t)slot * JSP + jh) * MM;
#pragma unroll
    for (int r = 0; r < 4; ++r) o[c16a + q * 4 + r] = cacc0[r];
    if (v1) {
#pragma unroll
      for (int r = 0; r < 4; ++r) o[c16b + q * 4 + r] = cacc1[r];
    }
  }
}

// K4b: finisher -> icn
__global__ void __launch_bounds__(256) k_cnorm_fin(const float* __restrict__ pcn,
                                                   const int* __restrict__ ivl,
                                                   float* __restrict__ icn) {
  int slot = blockIdx.x;
  int n, b, iv;
  if (!decode_slot(slot, ivl, n, b, iv)) return;
  int col = blockIdx.y * 256 + threadIdx.x;
  if (col >= MM) return;
  const float* p = pcn + (size_t)slot * JSP * MM;
  float s = p[col] + p[MM + col] + p[2 * MM + col];
  icn[(size_t)slot * MM + col] = 1.f / fmaxf(sqrtf(s), EPSF);
}

// ------------------------------------------------------------------
// K5: loss; partials pre-scaled by 1/((TC-iv)*BB*MM*MM*niv).
// ------------------------------------------------------------------
__global__ void __launch_bounds__(256) k_loss(const short8v* __restrict__ dsp,
                                              const int* __restrict__ ivl,
                                              const float* __restrict__ irn,
                                              const float* __restrict__ icn,
                                              int niv,
                                              double* __restrict__ partials) {
  int slot = blockIdx.x, jh = blockIdx.z;
  int wid = threadIdx.x >> 6, lane = threadIdx.x & 63;
  int rg = blockIdx.y * 4 + wid;
  if (rg >= RG) return;
  size_t pidx = ((size_t)slot * RG + rg) * JSP + jh;
  int n, b, iv;
  if (!decode_slot(slot, ivl, n, b, iv)) {
    if (lane == 0) partials[pidx] = 0.0;
    return;
  }
  int q = lane >> 4, li = lane & 15;
  int base = rg * 32;
  bool v1 = (base + 16) < MM;
  int r16a = base, r16b = v1 ? base + 16 : base;
  const short8v* D0 = dsp + (size_t)(n * BB + b) * 4 * MM;
  const short8v* B0 = dsp + (size_t)((n + iv) * BB + b) * 4 * MM + (size_t)q * MM + li;
  short8v ah0 = D0[(size_t)q * MM + r16a + li];
  short8v ah1 = D0[(size_t)q * MM + r16b + li];
  float uA[4], uB[4];
#pragma unroll
  for (int r = 0; r < 4; ++r) {
    uA[r] = irn[(size_t)slot * MM + r16a + q * 4 + r];
    uB[r] = v1 ? irn[(size_t)slot * MM + r16b + q * 4 + r] : 0.f;
  }
  const float* icnS = icn + (size_t)slot * MM + li;
  int jt0 = jh * JQ, jtN = jt0 + JQ;
  short8v bA = B0[jt0 * 16];
  short8v bB = B0[min(jt0 + 1, JT - 1) * 16];
  float icA = icnS[jt0 * 16];
  float icB = icnS[min(jt0 + 1, JT - 1) * 16];
  float lacc0 = 0.f, lacc1 = 0.f;
#pragma unroll 5
  for (int jt = jt0; jt < jtN; ++jt) {
    short8v bC = B0[min(jt + 2, JT - 1) * 16];
    float icC = icnS[min(jt + 2, JT - 1) * 16];
    float4v acc0 = s_tile1(ah0, bA);
    float4v acc1 = s_tile1(ah1, bA);
#pragma unroll
    for (int r = 0; r < 4; ++r) {
      lacc0 += fmaxf(fmaf(acc0[r], icA * uA[r], -0.2f), 0.f);
      lacc1 += fmaxf(fmaf(acc1[r], icA * uB[r], -0.2f), 0.f);
    }
    bA = bB; bB = bC; icA = icB; icB = icC;
  }
  float lacc = lacc0 + lacc1;
#pragma unroll
  for (int off = 32; off > 0; off >>= 1) lacc += __shfl_xor(lacc, off);
  if (lane == 0) {
    double scale = 1.0 / ((double)(TC - iv) * BB * (double)MM * (double)MM * (double)niv);
    partials[pidx] = (double)lacc * scale;
  }
}

// ------------------------------------------------------------------
// K5b: correction for masked cells; pre-scaled like k_loss.
// ------------------------------------------------------------------
__global__ void __launch_bounds__(256) k_corr(const short8v* __restrict__ dsp,
                                              const int* __restrict__ ivl,
                                              const float* __restrict__ irn,
                                              const float* __restrict__ icn,
                                              const float2* __restrict__ warped,
                                              int niv,
                                              double* __restrict__ partials2) {
  __shared__ double swsum[4];
  int slot = blockIdx.x, tile = blockIdx.y;
  int t = threadIdx.x;
  int n, b, iv;
  bool valid = decode_slot(slot, ivl, n, b, iv);
  double corr = 0.0;
  int row = tile * 256 + t;
  if (valid && row < MM) {
    float2 wp = warped[(size_t)slot * MM + row];
    int kx0 = max(0, (int)ceilf((wp.x - 7.5f) * 0.125f));
    int kx1 = min(WC - 1, (int)floorf((wp.x + 7.5f) * 0.125f));
    int ky0 = max(0, (int)ceilf((wp.y - 7.5f) * 0.125f));
    int ky1 = min(HC - 1, (int)floorf((wp.y + 7.5f) * 0.125f));
    if (kx0 <= kx1 && ky0 <= ky1) {
      const short8v* D0 = dsp + (size_t)(n * BB + b) * 4 * MM;
      const short8v* D1 = dsp + (size_t)((n + iv) * BB + b) * 4 * MM;
      float a[CF];
#pragma unroll
      for (int qq = 0; qq < 4; ++qq) {
        short8v h = D0[(size_t)qq * MM + row];
#pragma unroll
        for (int e = 0; e < 8; ++e) a[qq * 8 + e] = bf2f((unsigned short)h[e]);
      }
      float ir = irn[(size_t)slot * MM + row];
      float fcorr = 0.f;
      for (int ky = ky0; ky <= ky1; ++ky) {
        for (int kx = kx0; kx <= kx1; ++kx) {
          float dx = (float)(kx * 8) - wp.x;
          float dy = (float)(ky * 8) - wp.y;
          if (fmaf(dx, dx, dy * dy) <= 56.25f) {
            int j = ky * WC + kx;
            float dot = 0.f;
#pragma unroll
            for (int qq = 0; qq < 4; ++qq) {
              short8v h1 = D1[(size_t)qq * MM + j];
#pragma unroll
              for (int e = 0; e < 8; ++e)
                dot = fmaf(a[qq * 8 + e], bf2f((unsigned short)h1[e]), dot);
            }
            float s = fmaxf(dot, 0.f);
            float D = s * ir * icn[(size_t)slot * MM + j];
            fcorr += 0.05f * fmaxf(1.f - D, 0.f) - fmaxf(D - 0.2f, 0.f);
          }
        }
      }
      double scale = 1.0 / ((double)(TC - iv) * BB * (double)MM * (double)MM * (double)niv);
      corr = (double)fcorr * scale;
    }
  }
#pragma unroll
  for (int off = 32; off > 0; off >>= 1) corr += __shfl_down(corr, off);
  int wid = t >> 6, lane = t & 63;
  if (lane == 0) swsum[wid] = corr;
  __syncthreads();
  if (t == 0) partials2[(size_t)slot * CT + tile] = swsum[0] + swsum[1] + swsum[2] + swsum[3];
}

// ------------------------------------------------------------------
// K6a: stage-1 parallel reduction over all pre-scaled partials.
// ------------------------------------------------------------------
__global__ void __launch_bounds__(256) k_red1(const double* __restrict__ p1, int n1,
                                              const double* __restrict__ p2, int n2,
                                              double* __restrict__ red) {
  __shared__ double sw[4];
  int t = threadIdx.x, blk = blockIdx.x;
  double s = 0.0;
  for (int i = blk * 256 + t; i < n1; i += REDB * 256) s += p1[i];
  for (int i = blk * 256 + t; i < n2; i += REDB * 256) s += p2[i];
#pragma unroll
  for (int off = 32; off > 0; off >>= 1) s += __shfl_down(s, off);
  int wid = t >> 6, lane = t & 63;
  if (lane == 0) sw[wid] = s;
  __syncthreads();
  if (t == 0) red[blk] = sw[0] + sw[1] + sw[2] + sw[3];
}

// K6b: stage-2 -> scalar out
__global__ void k_red2(const double* __restrict__ red, float* __restrict__ out) {
  int lane = threadIdx.x; // 64 threads
  double s = (lane < REDB) ? red[lane] : 0.0;
#pragma unroll
  for (int off = 32; off > 0; off >>= 1) s += __shfl_down(s, off);
  if (lane == 0) out[0] = (float)s;
}

// ------------------------------------------------------------------
extern "C" void kernel_launch(void* const* d_in, const int* in_sizes, int n_in,
                              void* d_out, int out_size, void* d_ws, size_t ws_size,
                              hipStream_t stream) {
  const float* pred = (const float*)d_in[0];
  const float* rv   = (const float*)d_in[1];
  const float* tv   = (const float*)d_in[2];
  const float* nts  = (const float*)d_in[3];
  const float* dep  = (const float*)d_in[4];
  const float* Ks   = (const float*)d_in[5];
  const float* Kin  = (const float*)d_in[6];
  const float* osz  = (const float*)d_in[7];
  const int*   ivl  = (const int*)d_in[8];
  int niv = in_sizes[8];
  int slots = niv * NMAX * BB;

  char* ws = (char*)d_ws;
  size_t off = 0;
  short8v* dsp = (short8v*)(ws + off);  off += (size_t)TC * BB * 4 * MM * 16;
  float2* warped = (float2*)(ws + off); off += (size_t)slots * MM * 8;
  float* prn = (float*)(ws + off);      off += (size_t)slots * JSP * MM * 4;
  float* pcn = (float*)(ws + off);      off += (size_t)slots * JSP * MM * 4;
  float* irn = (float*)(ws + off);      off += (size_t)slots * MM * 4;
  float* icn = (float*)(ws + off);      off += (size_t)slots * MM * 4;
  off = (off + 255) & ~(size_t)255;
  double* partials = (double*)(ws + off);  off += (size_t)slots * RG * JSP * 8;
  double* partials2 = (double*)(ws + off); off += (size_t)slots * CT * 8;
  double* red = (double*)(ws + off);       off += (size_t)REDB * 8;

  int n1 = slots * RG * JSP;
  int n2 = slots * CT;

  hipLaunchKernelGGL(k_prep, dim3(TC * BB * 5 + slots), dim3(256), 0, stream,
                     pred, dsp, rv, tv, nts, dep, Ks, Kin, osz, ivl, warped);
  dim3 sgrid(slots, RGB, JSP);
  dim3 fgrid(slots, CT);
  hipLaunchKernelGGL(k_rnorm_p, sgrid, dim3(256), 0, stream, dsp, ivl, prn);
  hipLaunchKernelGGL(k_rnorm_fin, fgrid, dim3(256), 0, stream, prn, ivl, irn);
  hipLaunchKernelGGL(k_cnorm_p, sgrid, dim3(256), 0, stream, dsp, ivl, irn, pcn);
  hipLaunchKernelGGL(k_cnorm_fin, fgrid, dim3(256), 0, stream, pcn, ivl, icn);
  hipLaunchKernelGGL(k_loss, sgrid, dim3(256), 0, stream, dsp, ivl, irn, icn, niv, partials);
  hipLaunchKernelGGL(k_corr, fgrid, dim3(256), 0, stream,
                     dsp, ivl, irn, icn, warped, niv, partials2);
  hipLaunchKernelGGL(k_red1, dim3(REDB), dim3(256), 0, stream, partials, n1, partials2, n2, red);
  hipLaunchKernelGGL(k_red2, dim3(1), dim3(64), 0, stream, red, (float*)d_out);
}

// Round 10
// 76.896 us; speedup vs baseline: 1.5076x; 1.0525x over previous
//
#include <hip/hip_runtime.h>
#include <math.h>

// ---- problem constants ----
#define TT   5
#define CAM  4
#define TC   20
#define BB   2
#define CF   32
#define HC   30
#define WC   40
#define MM   1200
#define NMAX 19
#define EPSF 1e-12f
#define JT   75      // 16-col tiles per item
#define RG4  19      // row-groups of 64 rows per slot (ceil(1200/64))
#define RGB4 5       // ceil(RG4/4) y-blocks (4 waves per block)
#define JSP  5       // j-loop split factor
#define JQ   15      // JT / JSP (exact)
#define CT   5       // corr tiles of 256 rows
#define REDB 16      // stage-1 reduction blocks

typedef __attribute__((ext_vector_type(8))) short short8v;   // 8 bf16 (4 VGPR)
typedef __attribute__((ext_vector_type(4))) float float4v;

__device__ inline unsigned short f2bf(float x) {
  unsigned int u = __float_as_uint(x);
  unsigned int r = (u + 0x7FFFu + ((u >> 16) & 1u)) >> 16;  // RNE
  return (unsigned short)r;
}
__device__ inline float bf2f(unsigned short h) {
  return __uint_as_float(((unsigned int)h) << 16);
}

__device__ inline void rodrigues_d(const double rv[3], double R[9]) {
  double th = sqrt(rv[0]*rv[0] + rv[1]*rv[1] + rv[2]*rv[2]);
  double thc = fmax(th, 1e-12);
  double kx = rv[0] / thc, ky = rv[1] / thc, kz = rv[2] / thc;
  double st = sin(th), ct = cos(th);
  double Km[9] = { 0.0, -kz,  ky,  kz, 0.0, -kx,  -ky, kx, 0.0 };
  double K2[9];
  for (int r = 0; r < 3; ++r)
    for (int c = 0; c < 3; ++c)
      K2[r*3+c] = Km[r*3+0]*Km[0*3+c] + Km[r*3+1]*Km[1*3+c] + Km[r*3+2]*Km[2*3+c];
  for (int r = 0; r < 3; ++r)
    for (int c = 0; c < 3; ++c)
      R[r*3+c] = (r == c ? 1.0 : 0.0) + st * Km[r*3+c] + (1.0 - ct) * K2[r*3+c];
}
__device__ inline void mm3(const double* A, const double* B, double* C) {
  for (int r = 0; r < 3; ++r)
    for (int c = 0; c < 3; ++c)
      C[r*3+c] = A[r*3+0]*B[0*3+c] + A[r*3+1]*B[1*3+c] + A[r*3+2]*B[2*3+c];
}

__device__ inline bool decode_slot(int slot, const int* ivl, int& n, int& b, int& iv) {
  int ivi = slot / (NMAX * BB);
  int rem = slot % (NMAX * BB);
  n = rem / BB; b = rem % BB;
  iv = ivl[ivi];
  return n < TC - iv;
}

// ------------------------------------------------------------------
// K1 (fused): split role (blocks 0..TC*BB*5-1) + warp role (rest).
// ------------------------------------------------------------------
__global__ void k_prep(const float* __restrict__ pred, short8v* __restrict__ dsp,
                       const float* __restrict__ rv_, const float* __restrict__ tv_,
                       const float* __restrict__ nts_, const float* __restrict__ dep_,
                       const float* __restrict__ Ks_, const float* __restrict__ Kin_,
                       const float* __restrict__ osz_, const int* __restrict__ ivl,
                       float2* __restrict__ warped) {
  int bx = blockIdx.x;
  int tid = threadIdx.x;
  if (bx < TC * BB * 5) {
    int tb = bx / 5;
    int pix = (bx % 5) * 240 + tid;
    if (tid >= 240 || pix >= MM) return;
    const float* src = pred + (size_t)tb * CF * MM;
    short8v*     dst = dsp  + (size_t)tb * 4 * MM;
    float v[CF]; float ss = 0.f;
#pragma unroll
    for (int c = 0; c < CF; ++c) { float x = src[c * MM + pix]; v[c] = x; ss = fmaf(x, x, ss); }
    float inv = 1.f / fmaxf(sqrtf(ss), EPSF);
#pragma unroll
    for (int s = 0; s < 4; ++s) {
      short8v oh;
#pragma unroll
      for (int e = 0; e < 8; ++e) oh[e] = (short)f2bf(v[s*8+e] * inv);
      dst[(size_t)s * MM + pix] = oh;
    }
    return;
  }
  // ---- warp role ----
  int slot = bx - TC * BB * 5;
  int n, b, iv;
  if (!decode_slot(slot, ivl, n, b, iv)) return;
  int q0 = n, q1 = n + iv;
  int t0 = q0 / CAM, c0 = q0 % CAM;
  int t1 = q1 / CAM, c1 = q1 % CAM;
  size_t e0 = (size_t)(t0 * BB + b) * CAM + c0;
  size_t e1 = (size_t)(t1 * BB + b) * CAM + c1;

  double rv0[3], tv0[3], rv1[3], tv1[3], nv[3];
  for (int k = 0; k < 3; ++k) {
    rv0[k] = rv_[e0*3 + k]; tv0[k] = tv_[e0*3 + k];
    rv1[k] = rv_[e1*3 + k]; tv1[k] = tv_[e1*3 + k];
    nv[k]  = nts_[e0*3 + k];
  }
  double d = dep_[e0];
  double K9[9], Ki9[9];
  for (int k = 0; k < 9; ++k) { K9[k] = Ks_[e0*9 + k]; Ki9[k] = Kin_[e0*9 + k]; }

  double R0[9], R1[9], R[9];
  rodrigues_d(rv0, R0);
  rodrigues_d(rv1, R1);
  for (int r = 0; r < 3; ++r)
    for (int c = 0; c < 3; ++c)
      R[r*3+c] = R1[r*3+0]*R0[c*3+0] + R1[r*3+1]*R0[c*3+1] + R1[r*3+2]*R0[c*3+2];
  double tvec[3];
  for (int r = 0; r < 3; ++r)
    tvec[r] = tv1[r] - (R[r*3+0]*tv0[0] + R[r*3+1]*tv0[1] + R[r*3+2]*tv0[2]);
  double Mid[9];
  for (int r = 0; r < 3; ++r)
    for (int c = 0; c < 3; ++c)
      Mid[r*3+c] = R[r*3+c] - tvec[r] * nv[c] / d;
  double T1[9], Hm[9];
  mm3(K9, Mid, T1);
  mm3(T1, Ki9, Hm);

  double osz0 = osz_[e0*2 + 0], osz1 = osz_[e0*2 + 1];
  double s0 = 240.0 / osz0, s1 = 320.0 / osz1;
  double sv[3] = { s1, s0, 1.0 };
  double Hs[9];
  for (int r = 0; r < 3; ++r)
    for (int c = 0; c < 3; ++c)
      Hs[r*3+c] = Hm[r*3+c] * sv[r] / sv[c];

  float2* wout = warped + (size_t)slot * MM;
  for (int cell = tid; cell < MM; cell += blockDim.x) {
    double x = (double)((cell % WC) * 8);
    double y = (double)((cell / WC) * 8);
    double wx = Hs[0]*x + Hs[1]*y + Hs[2];
    double wy = Hs[3]*x + Hs[4]*y + Hs[5];
    double wz = Hs[6]*x + Hs[7]*y + Hs[8];
    float z = (float)wz;
    if (fabsf(z) < 1e-8f) z = 1e-8f;
    wout[cell] = make_float2((float)wx / z, (float)wy / z);
  }
}

__device__ inline float4v s_tile1(short8v ah, short8v bh) {
  float4v acc = {0.f, 0.f, 0.f, 0.f};
  return __builtin_amdgcn_mfma_f32_16x16x32_bf16(ah, bh, acc, 0, 0, 0);
}

// ------------------------------------------------------------------
// K3: partial row sum-of-squares. Wave owns 64 rows (4 tiles), each
// B-fragment feeds 4 MFMAs. 4 independent waves/block, fifth of j.
// C/D: col=lane&15, row=(lane>>4)*4+reg.
// ------------------------------------------------------------------
__global__ void __launch_bounds__(256) k_rnorm_p(const short8v* __restrict__ dsp,
                                                 const int* __restrict__ ivl,
                                                 float* __restrict__ prn) {
  int slot = blockIdx.x, jh = blockIdx.z;
  int n, b, iv;
  if (!decode_slot(slot, ivl, n, b, iv)) return;
  int wid = threadIdx.x >> 6, lane = threadIdx.x & 63;
  int rg = blockIdx.y * 4 + wid;
  if (rg >= RG4) return;
  int q = lane >> 4, li = lane & 15;
  int base = rg * 64;
  const short8v* D0 = dsp + (size_t)(n * BB + b) * 4 * MM;
  const short8v* B0 = dsp + (size_t)((n + iv) * BB + b) * 4 * MM + (size_t)q * MM + li;
  bool vt[4]; int rt[4];
  short8v ah[4];
  float4v racc[4];
#pragma unroll
  for (int t = 0; t < 4; ++t) {
    int rb = base + t * 16;
    vt[t] = rb < MM;
    rt[t] = vt[t] ? rb : 0;
    ah[t] = D0[(size_t)q * MM + rt[t] + li];
    racc[t] = (float4v){0.f, 0.f, 0.f, 0.f};
  }
  int jt0 = jh * JQ, jtN = jt0 + JQ;
  short8v bA = B0[jt0 * 16];
  short8v bB = B0[min(jt0 + 1, JT - 1) * 16];
#pragma unroll 3
  for (int jt = jt0; jt < jtN; ++jt) {
    short8v bC = B0[min(jt + 2, JT - 1) * 16];
#pragma unroll
    for (int t = 0; t < 4; ++t) {
      float4v acc = s_tile1(ah[t], bA);
#pragma unroll
      for (int r = 0; r < 4; ++r) {
        float x = fmaxf(acc[r], 0.f);
        racc[t][r] = fmaf(x, x, racc[t][r]);
      }
    }
    bA = bB; bB = bC;
  }
#pragma unroll
  for (int m = 1; m <= 8; m <<= 1)
#pragma unroll
    for (int t = 0; t < 4; ++t)
#pragma unroll
      for (int r = 0; r < 4; ++r)
        racc[t][r] += __shfl_xor(racc[t][r], m);
  if (li == 0) {
    float* o = prn + ((size_t)slot * JSP + jh) * MM;
#pragma unroll
    for (int t = 0; t < 4; ++t)
      if (vt[t]) {
#pragma unroll
        for (int r = 0; r < 4; ++r) o[rt[t] + q * 4 + r] = racc[t][r];
      }
  }
}

// K3b: finisher -> irn = 1/max(sqrt(sum of JSP partials), eps)
__global__ void __launch_bounds__(256) k_rnorm_fin(const float* __restrict__ prn,
                                                   const int* __restrict__ ivl,
                                                   float* __restrict__ irn) {
  int slot = blockIdx.x;
  int n, b, iv;
  if (!decode_slot(slot, ivl, n, b, iv)) return;
  int row = blockIdx.y * 256 + threadIdx.x;
  if (row >= MM) return;
  const float* p = prn + (size_t)slot * JSP * MM;
  float s = 0.f;
#pragma unroll
  for (int k = 0; k < JSP; ++k) s += p[k * MM + row];
  irn[(size_t)slot * MM + row] = 1.f / fmaxf(sqrtf(s), EPSF);
}

// ------------------------------------------------------------------
// K4: partial col sum-of-squares of (relu(S)·irn_i). Same 4-tile form.
// ------------------------------------------------------------------
__global__ void __launch_bounds__(256) k_cnorm_p(const short8v* __restrict__ dsp,
                                                 const int* __restrict__ ivl,
                                                 const float* __restrict__ irn,
                                                 float* __restrict__ pcn) {
  int slot = blockIdx.x, jh = blockIdx.z;
  int n, b, iv;
  if (!decode_slot(slot, ivl, n, b, iv)) return;
  int wid = threadIdx.x >> 6, lane = threadIdx.x & 63;
  int rg = blockIdx.y * 4 + wid;
  if (rg >= RG4) return;
  int q = lane >> 4, li = lane & 15;
  int base = rg * 64;
  const short8v* D1 = dsp + (size_t)((n + iv) * BB + b) * 4 * MM;
  const short8v* B0 = dsp + (size_t)(n * BB + b) * 4 * MM + (size_t)q * MM + li;
  bool vt[4]; int rt[4];
  short8v ah[4];
  float4v cacc[4];
#pragma unroll
  for (int t = 0; t < 4; ++t) {
    int rb = base + t * 16;
    vt[t] = rb < MM;
    rt[t] = vt[t] ? rb : 0;
    ah[t] = D1[(size_t)q * MM + rt[t] + li];
    cacc[t] = (float4v){0.f, 0.f, 0.f, 0.f};
  }
  const float* irnS = irn + (size_t)slot * MM + li;
  int jt0 = jh * JQ, jtN = jt0 + JQ;
  short8v bA = B0[jt0 * 16];
  short8v bB = B0[min(jt0 + 1, JT - 1) * 16];
  float irA = irnS[jt0 * 16];
  float irB = irnS[min(jt0 + 1, JT - 1) * 16];
#pragma unroll 3
  for (int jt = jt0; jt < jtN; ++jt) {
    short8v bC = B0[min(jt + 2, JT - 1) * 16];
    float irC = irnS[min(jt + 2, JT - 1) * 16];
#pragma unroll
    for (int t = 0; t < 4; ++t) {
      float4v acc = s_tile1(ah[t], bA);
#pragma unroll
      for (int r = 0; r < 4; ++r) {
        float x = fmaxf(acc[r], 0.f) * irA;
        cacc[t][r] = fmaf(x, x, cacc[t][r]);
      }
    }
    bA = bB; bB = bC; irA = irB; irB = irC;
  }
#pragma unroll
  for (int m = 1; m <= 8; m <<= 1)
#pragma unroll
    for (int t = 0; t < 4; ++t)
#pragma unroll
      for (int r = 0; r < 4; ++r)
        cacc[t][r] += __shfl_xor(cacc[t][r], m);
  if (li == 0) {
    float* o = pcn + ((size_t)slot * JSP + jh) * MM;
#pragma unroll
    for (int t = 0; t < 4; ++t)
      if (vt[t]) {
#pragma unroll
        for (int r = 0; r < 4; ++r) o[rt[t] + q * 4 + r] = cacc[t][r];
      }
  }
}

// K4b: finisher -> icn
__global__ void __launch_bounds__(256) k_cnorm_fin(const float* __restrict__ pcn,
                                                   const int* __restrict__ ivl,
                                                   float* __restrict__ icn) {
  int slot = blockIdx.x;
  int n, b, iv;
  if (!decode_slot(slot, ivl, n, b, iv)) return;
  int col = blockIdx.y * 256 + threadIdx.x;
  if (col >= MM) return;
  const float* p = pcn + (size_t)slot * JSP * MM;
  float s = 0.f;
#pragma unroll
  for (int k = 0; k < JSP; ++k) s += p[k * MM + col];
  icn[(size_t)slot * MM + col] = 1.f / fmaxf(sqrtf(s), EPSF);
}

// ------------------------------------------------------------------
// K5: loss; 4-tile, pre-scaled partials. Invalid tiles get u=0.
// ------------------------------------------------------------------
__global__ void __launch_bounds__(256) k_loss(const short8v* __restrict__ dsp,
                                              const int* __restrict__ ivl,
                                              const float* __restrict__ irn,
                                              const float* __restrict__ icn,
                                              int niv,
                                              double* __restrict__ partials) {
  int slot = blockIdx.x, jh = blockIdx.z;
  int wid = threadIdx.x >> 6, lane = threadIdx.x & 63;
  int rg = blockIdx.y * 4 + wid;
  if (rg >= RG4) return;
  size_t pidx = ((size_t)slot * RG4 + rg) * JSP + jh;
  int n, b, iv;
  if (!decode_slot(slot, ivl, n, b, iv)) {
    if (lane == 0) partials[pidx] = 0.0;
    return;
  }
  int q = lane >> 4, li = lane & 15;
  int base = rg * 64;
  const short8v* D0 = dsp + (size_t)(n * BB + b) * 4 * MM;
  const short8v* B0 = dsp + (size_t)((n + iv) * BB + b) * 4 * MM + (size_t)q * MM + li;
  short8v ah[4];
  float u[4][4];
#pragma unroll
  for (int t = 0; t < 4; ++t) {
    int rb = base + t * 16;
    bool vt = rb < MM;
    int rtc = vt ? rb : 0;
    ah[t] = D0[(size_t)q * MM + rtc + li];
#pragma unroll
    for (int r = 0; r < 4; ++r)
      u[t][r] = vt ? irn[(size_t)slot * MM + rtc + q * 4 + r] : 0.f;
  }
  const float* icnS = icn + (size_t)slot * MM + li;
  int jt0 = jh * JQ, jtN = jt0 + JQ;
  short8v bA = B0[jt0 * 16];
  short8v bB = B0[min(jt0 + 1, JT - 1) * 16];
  float icA = icnS[jt0 * 16];
  float icB = icnS[min(jt0 + 1, JT - 1) * 16];
  float lacc0 = 0.f, lacc1 = 0.f;
#pragma unroll 3
  for (int jt = jt0; jt < jtN; ++jt) {
    short8v bC = B0[min(jt + 2, JT - 1) * 16];
    float icC = icnS[min(jt + 2, JT - 1) * 16];
#pragma unroll
    for (int t = 0; t < 4; ++t) {
      float4v acc = s_tile1(ah[t], bA);
      float s0 = fmaxf(fmaf(acc[0], icA * u[t][0], -0.2f), 0.f)
               + fmaxf(fmaf(acc[1], icA * u[t][1], -0.2f), 0.f);
      float s1 = fmaxf(fmaf(acc[2], icA * u[t][2], -0.2f), 0.f)
               + fmaxf(fmaf(acc[3], icA * u[t][3], -0.2f), 0.f);
      lacc0 += s0; lacc1 += s1;
    }
    bA = bB; bB = bC; icA = icB; icB = icC;
  }
  float lacc = lacc0 + lacc1;
#pragma unroll
  for (int off = 32; off > 0; off >>= 1) lacc += __shfl_xor(lacc, off);
  if (lane == 0) {
    double scale = 1.0 / ((double)(TC - iv) * BB * (double)MM * (double)MM * (double)niv);
    partials[pidx] = (double)lacc * scale;
  }
}

// ------------------------------------------------------------------
// K5b: correction for masked cells; pre-scaled like k_loss.
// ------------------------------------------------------------------
__global__ void __launch_bounds__(256) k_corr(const short8v* __restrict__ dsp,
                                              const int* __restrict__ ivl,
                                              const float* __restrict__ irn,
                                              const float* __restrict__ icn,
                                              const float2* __restrict__ warped,
                                              int niv,
                                              double* __restrict__ partials2) {
  __shared__ double swsum[4];
  int slot = blockIdx.x, tile = blockIdx.y;
  int t = threadIdx.x;
  int n, b, iv;
  bool valid = decode_slot(slot, ivl, n, b, iv);
  double corr = 0.0;
  int row = tile * 256 + t;
  if (valid && row < MM) {
    float2 wp = warped[(size_t)slot * MM + row];
    int kx0 = max(0, (int)ceilf((wp.x - 7.5f) * 0.125f));
    int kx1 = min(WC - 1, (int)floorf((wp.x + 7.5f) * 0.125f));
    int ky0 = max(0, (int)ceilf((wp.y - 7.5f) * 0.125f));
    int ky1 = min(HC - 1, (int)floorf((wp.y + 7.5f) * 0.125f));
    if (kx0 <= kx1 && ky0 <= ky1) {
      const short8v* D0 = dsp + (size_t)(n * BB + b) * 4 * MM;
      const short8v* D1 = dsp + (size_t)((n + iv) * BB + b) * 4 * MM;
      float a[CF];
#pragma unroll
      for (int qq = 0; qq < 4; ++qq) {
        short8v h = D0[(size_t)qq * MM + row];
#pragma unroll
        for (int e = 0; e < 8; ++e) a[qq * 8 + e] = bf2f((unsigned short)h[e]);
      }
      float ir = irn[(size_t)slot * MM + row];
      float fcorr = 0.f;
      for (int ky = ky0; ky <= ky1; ++ky) {
        for (int kx = kx0; kx <= kx1; ++kx) {
          float dx = (float)(kx * 8) - wp.x;
          float dy = (float)(ky * 8) - wp.y;
          if (fmaf(dx, dx, dy * dy) <= 56.25f) {
            int j = ky * WC + kx;
            float dot = 0.f;
#pragma unroll
            for (int qq = 0; qq < 4; ++qq) {
              short8v h1 = D1[(size_t)qq * MM + j];
#pragma unroll
              for (int e = 0; e < 8; ++e)
                dot = fmaf(a[qq * 8 + e], bf2f((unsigned short)h1[e]), dot);
            }
            float s = fmaxf(dot, 0.f);
            float D = s * ir * icn[(size_t)slot * MM + j];
            fcorr += 0.05f * fmaxf(1.f - D, 0.f) - fmaxf(D - 0.2f, 0.f);
          }
        }
      }
      double scale = 1.0 / ((double)(TC - iv) * BB * (double)MM * (double)MM * (double)niv);
      corr = (double)fcorr * scale;
    }
  }
#pragma unroll
  for (int off = 32; off > 0; off >>= 1) corr += __shfl_down(corr, off);
  int wid = t >> 6, lane = t & 63;
  if (lane == 0) swsum[wid] = corr;
  __syncthreads();
  if (t == 0) partials2[(size_t)slot * CT + tile] = swsum[0] + swsum[1] + swsum[2] + swsum[3];
}

// ------------------------------------------------------------------
// K6a: stage-1 parallel reduction over all pre-scaled partials.
// ------------------------------------------------------------------
__global__ void __launch_bounds__(256) k_red1(const double* __restrict__ p1, int n1,
                                              const double* __restrict__ p2, int n2,
                                              double* __restrict__ red) {
  __shared__ double sw[4];
  int t = threadIdx.x, blk = blockIdx.x;
  double s = 0.0;
  for (int i = blk * 256 + t; i < n1; i += REDB * 256) s += p1[i];
  for (int i = blk * 256 + t; i < n2; i += REDB * 256) s += p2[i];
#pragma unroll
  for (int off = 32; off > 0; off >>= 1) s += __shfl_down(s, off);
  int wid = t >> 6, lane = t & 63;
  if (lane == 0) sw[wid] = s;
  __syncthreads();
  if (t == 0) red[blk] = sw[0] + sw[1] + sw[2] + sw[3];
}

// K6b: stage-2 -> scalar out
__global__ void k_red2(const double* __restrict__ red, float* __restrict__ out) {
  int lane = threadIdx.x; // 64 threads
  double s = (lane < REDB) ? red[lane] : 0.0;
#pragma unroll
  for (int off = 32; off > 0; off >>= 1) s += __shfl_down(s, off);
  if (lane == 0) out[0] = (float)s;
}

// ------------------------------------------------------------------
extern "C" void kernel_launch(void* const* d_in, const int* in_sizes, int n_in,
                              void* d_out, int out_size, void* d_ws, size_t ws_size,
                              hipStream_t stream) {
  const float* pred = (const float*)d_in[0];
  const float* rv   = (const float*)d_in[1];
  const float* tv   = (const float*)d_in[2];
  const float* nts  = (const float*)d_in[3];
  const float* dep  = (const float*)d_in[4];
  const float* Ks   = (const float*)d_in[5];
  const float* Kin  = (const float*)d_in[6];
  const float* osz  = (const float*)d_in[7];
  const int*   ivl  = (const int*)d_in[8];
  int niv = in_sizes[8];
  int slots = niv * NMAX * BB;

  char* ws = (char*)d_ws;
  size_t off = 0;
  short8v* dsp = (short8v*)(ws + off);  off += (size_t)TC * BB * 4 * MM * 16;
  float2* warped = (float2*)(ws + off); off += (size_t)slots * MM * 8;
  float* prn = (float*)(ws + off);      off += (size_t)slots * JSP * MM * 4;
  float* pcn = (float*)(ws + off);      off += (size_t)slots * JSP * MM * 4;
  float* irn = (float*)(ws + off);      off += (size_t)slots * MM * 4;
  float* icn = (float*)(ws + off);      off += (size_t)slots * MM * 4;
  off = (off + 255) & ~(size_t)255;
  double* partials = (double*)(ws + off);  off += (size_t)slots * RG4 * JSP * 8;
  double* partials2 = (double*)(ws + off); off += (size_t)slots * CT * 8;
  double* red = (double*)(ws + off);       off += (size_t)REDB * 8;

  int n1 = slots * RG4 * JSP;
  int n2 = slots * CT;

  hipLaunchKernelGGL(k_prep, dim3(TC * BB * 5 + slots), dim3(256), 0, stream,
                     pred, dsp, rv, tv, nts, dep, Ks, Kin, osz, ivl, warped);
  dim3 sgrid(slots, RGB4, JSP);
  dim3 fgrid(slots, CT);
  hipLaunchKernelGGL(k_rnorm_p, sgrid, dim3(256), 0, stream, dsp, ivl, prn);
  hipLaunchKernelGGL(k_rnorm_fin, fgrid, dim3(256), 0, stream, prn, ivl, irn);
  hipLaunchKernelGGL(k_cnorm_p, sgrid, dim3(256), 0, stream, dsp, ivl, irn, pcn);
  hipLaunchKernelGGL(k_cnorm_fin, fgrid, dim3(256), 0, stream, pcn, ivl, icn);
  hipLaunchKernelGGL(k_loss, sgrid, dim3(256), 0, stream, dsp, ivl, irn, icn, niv, partials);
  hipLaunchKernelGGL(k_corr, fgrid, dim3(256), 0, stream,
                     dsp, ivl, irn, icn, warped, niv, partials2);
  hipLaunchKernelGGL(k_red1, dim3(REDB), dim3(256), 0, stream, partials, n1, partials2, n2, red);
  hipLaunchKernelGGL(k_red2, dim3(1), dim3(64), 0, stream, red, (float*)d_out);
}

// Round 11
// 75.524 us; speedup vs baseline: 1.5350x; 1.0182x over previous
//
#include <hip/hip_runtime.h>
#include <math.h>

// ---- problem constants ----
#define TT   5
#define CAM  4
#define TC   20
#define BB   2
#define CF   32
#define HC   30
#define WC   40
#define MM   1200
#define NMAX 19
#define EPSF 1e-12f
#define EPS2 1e-24f   // 1/max(sqrt(s),EPSF) == rsqrt(max(s,EPS2))
#define JT   75      // 16-col tiles per item
#define RG4  19      // row-groups of 64 rows per slot (ceil(1200/64))
#define RGB4 5       // ceil(RG4/4) y-blocks (4 waves per block)
#define JSP  5       // j-loop split factor
#define JQ   15      // JT / JSP (exact)
#define CT   5       // corr tiles of 256 rows (== RGB4)

typedef __attribute__((ext_vector_type(8))) short short8v;   // 8 bf16 (4 VGPR)
typedef __attribute__((ext_vector_type(4))) float float4v;

__device__ inline unsigned short f2bf(float x) {
  unsigned int u = __float_as_uint(x);
  unsigned int r = (u + 0x7FFFu + ((u >> 16) & 1u)) >> 16;  // RNE
  return (unsigned short)r;
}
__device__ inline float bf2f(unsigned short h) {
  return __uint_as_float(((unsigned int)h) << 16);
}

__device__ inline void rodrigues_d(const double rv[3], double R[9]) {
  double th = sqrt(rv[0]*rv[0] + rv[1]*rv[1] + rv[2]*rv[2]);
  double thc = fmax(th, 1e-12);
  double kx = rv[0] / thc, ky = rv[1] / thc, kz = rv[2] / thc;
  double st = sin(th), ct = cos(th);
  double Km[9] = { 0.0, -kz,  ky,  kz, 0.0, -kx,  -ky, kx, 0.0 };
  double K2[9];
  for (int r = 0; r < 3; ++r)
    for (int c = 0; c < 3; ++c)
      K2[r*3+c] = Km[r*3+0]*Km[0*3+c] + Km[r*3+1]*Km[1*3+c] + Km[r*3+2]*Km[2*3+c];
  for (int r = 0; r < 3; ++r)
    for (int c = 0; c < 3; ++c)
      R[r*3+c] = (r == c ? 1.0 : 0.0) + st * Km[r*3+c] + (1.0 - ct) * K2[r*3+c];
}
__device__ inline void mm3(const double* A, const double* B, double* C) {
  for (int r = 0; r < 3; ++r)
    for (int c = 0; c < 3; ++c)
      C[r*3+c] = A[r*3+0]*B[0*3+c] + A[r*3+1]*B[1*3+c] + A[r*3+2]*B[2*3+c];
}

__device__ inline bool decode_slot(int slot, const int* ivl, int& n, int& b, int& iv) {
  int ivi = slot / (NMAX * BB);
  int rem = slot % (NMAX * BB);
  n = rem / BB; b = rem % BB;
  iv = ivl[ivi];
  return n < TC - iv;
}

// ------------------------------------------------------------------
// K1 (fused): split role (blocks 0..TC*BB*5-1) + warp role (rest).
// ------------------------------------------------------------------
__global__ void k_prep(const float* __restrict__ pred, short8v* __restrict__ dsp,
                       const float* __restrict__ rv_, const float* __restrict__ tv_,
                       const float* __restrict__ nts_, const float* __restrict__ dep_,
                       const float* __restrict__ Ks_, const float* __restrict__ Kin_,
                       const float* __restrict__ osz_, const int* __restrict__ ivl,
                       float2* __restrict__ warped) {
  int bx = blockIdx.x;
  int tid = threadIdx.x;
  if (bx < TC * BB * 5) {
    int tb = bx / 5;
    int pix = (bx % 5) * 240 + tid;
    if (tid >= 240 || pix >= MM) return;
    const float* src = pred + (size_t)tb * CF * MM;
    short8v*     dst = dsp  + (size_t)tb * 4 * MM;
    float v[CF]; float ss = 0.f;
#pragma unroll
    for (int c = 0; c < CF; ++c) { float x = src[c * MM + pix]; v[c] = x; ss = fmaf(x, x, ss); }
    float inv = 1.f / fmaxf(sqrtf(ss), EPSF);
#pragma unroll
    for (int s = 0; s < 4; ++s) {
      short8v oh;
#pragma unroll
      for (int e = 0; e < 8; ++e) oh[e] = (short)f2bf(v[s*8+e] * inv);
      dst[(size_t)s * MM + pix] = oh;
    }
    return;
  }
  // ---- warp role ----
  int slot = bx - TC * BB * 5;
  int n, b, iv;
  if (!decode_slot(slot, ivl, n, b, iv)) return;
  int q0 = n, q1 = n + iv;
  int t0 = q0 / CAM, c0 = q0 % CAM;
  int t1 = q1 / CAM, c1 = q1 % CAM;
  size_t e0 = (size_t)(t0 * BB + b) * CAM + c0;
  size_t e1 = (size_t)(t1 * BB + b) * CAM + c1;

  double rv0[3], tv0[3], rv1[3], tv1[3], nv[3];
  for (int k = 0; k < 3; ++k) {
    rv0[k] = rv_[e0*3 + k]; tv0[k] = tv_[e0*3 + k];
    rv1[k] = rv_[e1*3 + k]; tv1[k] = tv_[e1*3 + k];
    nv[k]  = nts_[e0*3 + k];
  }
  double d = dep_[e0];
  double K9[9], Ki9[9];
  for (int k = 0; k < 9; ++k) { K9[k] = Ks_[e0*9 + k]; Ki9[k] = Kin_[e0*9 + k]; }

  double R0[9], R1[9], R[9];
  rodrigues_d(rv0, R0);
  rodrigues_d(rv1, R1);
  for (int r = 0; r < 3; ++r)
    for (int c = 0; c < 3; ++c)
      R[r*3+c] = R1[r*3+0]*R0[c*3+0] + R1[r*3+1]*R0[c*3+1] + R1[r*3+2]*R0[c*3+2];
  double tvec[3];
  for (int r = 0; r < 3; ++r)
    tvec[r] = tv1[r] - (R[r*3+0]*tv0[0] + R[r*3+1]*tv0[1] + R[r*3+2]*tv0[2]);
  double Mid[9];
  for (int r = 0; r < 3; ++r)
    for (int c = 0; c < 3; ++c)
      Mid[r*3+c] = R[r*3+c] - tvec[r] * nv[c] / d;
  double T1[9], Hm[9];
  mm3(K9, Mid, T1);
  mm3(T1, Ki9, Hm);

  double osz0 = osz_[e0*2 + 0], osz1 = osz_[e0*2 + 1];
  double s0 = 240.0 / osz0, s1 = 320.0 / osz1;
  double sv[3] = { s1, s0, 1.0 };
  double Hs[9];
  for (int r = 0; r < 3; ++r)
    for (int c = 0; c < 3; ++c)
      Hs[r*3+c] = Hm[r*3+c] * sv[r] / sv[c];

  float2* wout = warped + (size_t)slot * MM;
  for (int cell = tid; cell < MM; cell += blockDim.x) {
    double x = (double)((cell % WC) * 8);
    double y = (double)((cell / WC) * 8);
    double wx = Hs[0]*x + Hs[1]*y + Hs[2];
    double wy = Hs[3]*x + Hs[4]*y + Hs[5];
    double wz = Hs[6]*x + Hs[7]*y + Hs[8];
    float z = (float)wz;
    if (fabsf(z) < 1e-8f) z = 1e-8f;
    wout[cell] = make_float2((float)wx / z, (float)wy / z);
  }
}

__device__ inline float4v s_tile1(short8v ah, short8v bh) {
  float4v acc = {0.f, 0.f, 0.f, 0.f};
  return __builtin_amdgcn_mfma_f32_16x16x32_bf16(ah, bh, acc, 0, 0, 0);
}

// ------------------------------------------------------------------
// K3: partial row sum-of-squares. Wave owns 64 rows (4 tiles), 4
// independent waves/block, fifth of j. No norms needed -> no LDS.
// ------------------------------------------------------------------
__global__ void __launch_bounds__(256) k_rnorm_p(const short8v* __restrict__ dsp,
                                                 const int* __restrict__ ivl,
                                                 float* __restrict__ prn) {
  int slot = blockIdx.x, jh = blockIdx.z;
  int n, b, iv;
  if (!decode_slot(slot, ivl, n, b, iv)) return;
  int wid = threadIdx.x >> 6, lane = threadIdx.x & 63;
  int rg = blockIdx.y * 4 + wid;
  if (rg >= RG4) return;
  int q = lane >> 4, li = lane & 15;
  int base = rg * 64;
  const short8v* D0 = dsp + (size_t)(n * BB + b) * 4 * MM;
  const short8v* B0 = dsp + (size_t)((n + iv) * BB + b) * 4 * MM + (size_t)q * MM + li;
  bool vt[4]; int rt[4];
  short8v ah[4];
  float4v racc[4];
#pragma unroll
  for (int t = 0; t < 4; ++t) {
    int rb = base + t * 16;
    vt[t] = rb < MM;
    rt[t] = vt[t] ? rb : 0;
    ah[t] = D0[(size_t)q * MM + rt[t] + li];
    racc[t] = (float4v){0.f, 0.f, 0.f, 0.f};
  }
  int jt0 = jh * JQ, jtN = jt0 + JQ;
  short8v bA = B0[jt0 * 16];
  short8v bB = B0[min(jt0 + 1, jtN - 1) * 16];
#pragma unroll 3
  for (int jt = jt0; jt < jtN; ++jt) {
    short8v bC = B0[min(jt + 2, jtN - 1) * 16];
#pragma unroll
    for (int t = 0; t < 4; ++t) {
      float4v acc = s_tile1(ah[t], bA);
#pragma unroll
      for (int r = 0; r < 4; ++r) {
        float x = fmaxf(acc[r], 0.f);
        racc[t][r] = fmaf(x, x, racc[t][r]);
      }
    }
    bA = bB; bB = bC;
  }
#pragma unroll
  for (int m = 1; m <= 8; m <<= 1)
#pragma unroll
    for (int t = 0; t < 4; ++t)
#pragma unroll
      for (int r = 0; r < 4; ++r)
        racc[t][r] += __shfl_xor(racc[t][r], m);
  if (li == 0) {
    float* o = prn + ((size_t)slot * JSP + jh) * MM;
#pragma unroll
    for (int t = 0; t < 4; ++t)
      if (vt[t]) {
#pragma unroll
        for (int r = 0; r < 4; ++r) o[rt[t] + q * 4 + r] = racc[t][r];
      }
  }
}

// ------------------------------------------------------------------
// K4: partial col sum-of-squares of (relu(S)·irn_i). irn computed
// cooperatively from prn into LDS (240 contiguous i's per block).
// Barrier precedes any per-wave exit.
// ------------------------------------------------------------------
__global__ void __launch_bounds__(256) k_cnorm_p(const short8v* __restrict__ dsp,
                                                 const int* __restrict__ ivl,
                                                 const float* __restrict__ prn,
                                                 float* __restrict__ pcn) {
  __shared__ float sIR[240];
  int slot = blockIdx.x, jh = blockIdx.z;
  int n, b, iv;
  if (!decode_slot(slot, ivl, n, b, iv)) return;   // uniform per block
  int t = threadIdx.x;
  int jt0 = jh * JQ, jtN = jt0 + JQ;
  const float* prnS = prn + (size_t)slot * JSP * MM;
  if (t < 240) {
    int i = jt0 * 16 + t;
    float s = 0.f;
#pragma unroll
    for (int k = 0; k < JSP; ++k) s += prnS[k * MM + i];
    sIR[t] = rsqrtf(fmaxf(s, EPS2));
  }
  __syncthreads();
  int wid = t >> 6, lane = t & 63;
  int rg = blockIdx.y * 4 + wid;
  if (rg >= RG4) return;
  int q = lane >> 4, li = lane & 15;
  int base = rg * 64;
  const short8v* D1 = dsp + (size_t)((n + iv) * BB + b) * 4 * MM;
  const short8v* B0 = dsp + (size_t)(n * BB + b) * 4 * MM + (size_t)q * MM + li;
  bool vt[4]; int rt[4];
  short8v ah[4];
  float4v cacc[4];
#pragma unroll
  for (int tt = 0; tt < 4; ++tt) {
    int rb = base + tt * 16;
    vt[tt] = rb < MM;
    rt[tt] = vt[tt] ? rb : 0;
    ah[tt] = D1[(size_t)q * MM + rt[tt] + li];
    cacc[tt] = (float4v){0.f, 0.f, 0.f, 0.f};
  }
  short8v bA = B0[jt0 * 16];
  short8v bB = B0[min(jt0 + 1, jtN - 1) * 16];
  float irA = sIR[li];
  float irB = sIR[(min(jt0 + 1, jtN - 1) - jt0) * 16 + li];
#pragma unroll 3
  for (int jt = jt0; jt < jtN; ++jt) {
    int jn = min(jt + 2, jtN - 1);
    short8v bC = B0[jn * 16];
    float irC = sIR[(jn - jt0) * 16 + li];
#pragma unroll
    for (int tt = 0; tt < 4; ++tt) {
      float4v acc = s_tile1(ah[tt], bA);
#pragma unroll
      for (int r = 0; r < 4; ++r) {
        float x = fmaxf(acc[r], 0.f) * irA;
        cacc[tt][r] = fmaf(x, x, cacc[tt][r]);
      }
    }
    bA = bB; bB = bC; irA = irB; irB = irC;
  }
#pragma unroll
  for (int m = 1; m <= 8; m <<= 1)
#pragma unroll
    for (int tt = 0; tt < 4; ++tt)
#pragma unroll
      for (int r = 0; r < 4; ++r)
        cacc[tt][r] += __shfl_xor(cacc[tt][r], m);
  if (li == 0) {
    float* o = pcn + ((size_t)slot * JSP + jh) * MM;
#pragma unroll
    for (int tt = 0; tt < 4; ++tt)
      if (vt[tt]) {
#pragma unroll
        for (int r = 0; r < 4; ++r) o[rt[tt] + q * 4 + r] = cacc[tt][r];
      }
  }
}

// ------------------------------------------------------------------
// K5 (fused): z<JSP -> loss role (irn folded into A-fragment, icn via
// LDS); z==JSP -> corr role (tile = blockIdx.y).
// ------------------------------------------------------------------
__global__ void __launch_bounds__(256) k_lc(const short8v* __restrict__ dsp,
                                            const int* __restrict__ ivl,
                                            const float* __restrict__ prn,
                                            const float* __restrict__ pcn,
                                            const float2* __restrict__ warped,
                                            int niv,
                                            double* __restrict__ partials,
                                            double* __restrict__ partials2) {
  __shared__ float sIC[240];
  __shared__ float sLIR[256];
  __shared__ double swsum[4];
  int slot = blockIdx.x, y = blockIdx.y, z = blockIdx.z;
  int t = threadIdx.x;
  int n, b, iv;
  bool valid = decode_slot(slot, ivl, n, b, iv);
  const float* prnS = prn + (size_t)slot * JSP * MM;
  const float* pcnS = pcn + (size_t)slot * JSP * MM;

  if (z == JSP) {
    // ---- corr role: masked cells (<=4/row), norms from partials ----
    double corr = 0.0;
    int row = y * 256 + t;
    if (valid && row < MM) {
      float2 wp = warped[(size_t)slot * MM + row];
      int kx0 = max(0, (int)ceilf((wp.x - 7.5f) * 0.125f));
      int kx1 = min(WC - 1, (int)floorf((wp.x + 7.5f) * 0.125f));
      int ky0 = max(0, (int)ceilf((wp.y - 7.5f) * 0.125f));
      int ky1 = min(HC - 1, (int)floorf((wp.y + 7.5f) * 0.125f));
      if (kx0 <= kx1 && ky0 <= ky1) {
        const short8v* D0 = dsp + (size_t)(n * BB + b) * 4 * MM;
        const short8v* D1 = dsp + (size_t)((n + iv) * BB + b) * 4 * MM;
        float a[CF];
#pragma unroll
        for (int qq = 0; qq < 4; ++qq) {
          short8v h = D0[(size_t)qq * MM + row];
#pragma unroll
          for (int e = 0; e < 8; ++e) a[qq * 8 + e] = bf2f((unsigned short)h[e]);
        }
        float irs = 0.f;
#pragma unroll
        for (int k = 0; k < JSP; ++k) irs += prnS[k * MM + row];
        float ir = rsqrtf(fmaxf(irs, EPS2));
        float fcorr = 0.f;
        for (int ky = ky0; ky <= ky1; ++ky) {
          for (int kx = kx0; kx <= kx1; ++kx) {
            float dx = (float)(kx * 8) - wp.x;
            float dy = (float)(ky * 8) - wp.y;
            if (fmaf(dx, dx, dy * dy) <= 56.25f) {
              int j = ky * WC + kx;
              float dot = 0.f;
#pragma unroll
              for (int qq = 0; qq < 4; ++qq) {
                short8v h1 = D1[(size_t)qq * MM + j];
#pragma unroll
                for (int e = 0; e < 8; ++e)
                  dot = fmaf(a[qq * 8 + e], bf2f((unsigned short)h1[e]), dot);
              }
              float ics = 0.f;
#pragma unroll
              for (int k = 0; k < JSP; ++k) ics += pcnS[k * MM + j];
              float ic = rsqrtf(fmaxf(ics, EPS2));
              float s = fmaxf(dot, 0.f);
              float D = s * ir * ic;
              fcorr += 0.05f * fmaxf(1.f - D, 0.f) - fmaxf(D - 0.2f, 0.f);
            }
          }
        }
        double scale = 1.0 / ((double)(TC - iv) * BB * (double)MM * (double)MM * (double)niv);
        corr = (double)fcorr * scale;
      }
    }
#pragma unroll
    for (int off = 32; off > 0; off >>= 1) corr += __shfl_down(corr, off);
    int wid = t >> 6, lane = t & 63;
    if (lane == 0) swsum[wid] = corr;
    __syncthreads();
    if (t == 0) partials2[(size_t)slot * CT + y] = swsum[0] + swsum[1] + swsum[2] + swsum[3];
    return;
  }

  // ---- loss role ----
  int wid = t >> 6, lane = t & 63;
  int rg = y * 4 + wid;
  if (!valid) {
    if (lane == 0 && rg < RG4) partials[((size_t)slot * RG4 + rg) * JSP + z] = 0.0;
    return;
  }
  int jt0 = z * JQ, jtN = jt0 + JQ;
  if (t < 240) {
    int j = jt0 * 16 + t;
    float s = 0.f;
#pragma unroll
    for (int k = 0; k < JSP; ++k) s += pcnS[k * MM + j];
    sIC[t] = rsqrtf(fmaxf(s, EPS2));
  }
  {
    int row = y * 256 + t;
    float v = 0.f;
    if (row < MM) {
      float s = 0.f;
#pragma unroll
      for (int k = 0; k < JSP; ++k) s += prnS[k * MM + row];
      v = rsqrtf(fmaxf(s, EPS2));
    }
    sLIR[t] = v;
  }
  __syncthreads();
  if (rg >= RG4) return;
  int q = lane >> 4, li = lane & 15;
  int base = rg * 64;
  const short8v* D0 = dsp + (size_t)(n * BB + b) * 4 * MM;
  const short8v* B0 = dsp + (size_t)((n + iv) * BB + b) * 4 * MM + (size_t)q * MM + li;
  short8v ah[4];
#pragma unroll
  for (int t4 = 0; t4 < 4; ++t4) {
    int rb = base + t4 * 16;
    bool vt = rb < MM;
    int rtc = vt ? rb : 0;
    short8v a = D0[(size_t)q * MM + rtc + li];
    float sc = vt ? sLIR[wid * 64 + t4 * 16 + li] : 0.f;   // irn[row] folded into A
#pragma unroll
    for (int e = 0; e < 8; ++e)
      a[e] = (short)f2bf(bf2f((unsigned short)a[e]) * sc);
    ah[t4] = a;
  }
  short8v bA = B0[jt0 * 16];
  short8v bB = B0[min(jt0 + 1, jtN - 1) * 16];
  float icA = sIC[li];
  float icB = sIC[(min(jt0 + 1, jtN - 1) - jt0) * 16 + li];
  float lacc0 = 0.f, lacc1 = 0.f;
#pragma unroll 3
  for (int jt = jt0; jt < jtN; ++jt) {
    int jn = min(jt + 2, jtN - 1);
    short8v bC = B0[jn * 16];
    float icC = sIC[(jn - jt0) * 16 + li];
#pragma unroll
    for (int t4 = 0; t4 < 4; ++t4) {
      float4v acc = s_tile1(ah[t4], bA);
      lacc0 += fmaxf(fmaf(acc[0], icA, -0.2f), 0.f)
             + fmaxf(fmaf(acc[1], icA, -0.2f), 0.f);
      lacc1 += fmaxf(fmaf(acc[2], icA, -0.2f), 0.f)
             + fmaxf(fmaf(acc[3], icA, -0.2f), 0.f);
    }
    bA = bB; bB = bC; icA = icB; icB = icC;
  }
  float lacc = lacc0 + lacc1;
#pragma unroll
  for (int off = 32; off > 0; off >>= 1) lacc += __shfl_xor(lacc, off);
  if (lane == 0) {
    double scale = 1.0 / ((double)(TC - iv) * BB * (double)MM * (double)MM * (double)niv);
    partials[((size_t)slot * RG4 + rg) * JSP + z] = (double)lacc * scale;
  }
}

// ------------------------------------------------------------------
// K6: single-block final reduction over all pre-scaled partials.
// ------------------------------------------------------------------
__global__ void __launch_bounds__(256) k_red(const double* __restrict__ p1, int n1,
                                             const double* __restrict__ p2, int n2,
                                             float* __restrict__ out) {
  __shared__ double sw[4];
  int t = threadIdx.x;
  double s = 0.0;
  for (int i = t; i < n1; i += 256) s += p1[i];
  for (int i = t; i < n2; i += 256) s += p2[i];
#pragma unroll
  for (int off = 32; off > 0; off >>= 1) s += __shfl_down(s, off);
  int wid = t >> 6, lane = t & 63;
  if (lane == 0) sw[wid] = s;
  __syncthreads();
  if (t == 0) out[0] = (float)(sw[0] + sw[1] + sw[2] + sw[3]);
}

// ------------------------------------------------------------------
extern "C" void kernel_launch(void* const* d_in, const int* in_sizes, int n_in,
                              void* d_out, int out_size, void* d_ws, size_t ws_size,
                              hipStream_t stream) {
  const float* pred = (const float*)d_in[0];
  const float* rv   = (const float*)d_in[1];
  const float* tv   = (const float*)d_in[2];
  const float* nts  = (const float*)d_in[3];
  const float* dep  = (const float*)d_in[4];
  const float* Ks   = (const float*)d_in[5];
  const float* Kin  = (const float*)d_in[6];
  const float* osz  = (const float*)d_in[7];
  const int*   ivl  = (const int*)d_in[8];
  int niv = in_sizes[8];
  int slots = niv * NMAX * BB;

  char* ws = (char*)d_ws;
  size_t off = 0;
  short8v* dsp = (short8v*)(ws + off);  off += (size_t)TC * BB * 4 * MM * 16;
  float2* warped = (float2*)(ws + off); off += (size_t)slots * MM * 8;
  float* prn = (float*)(ws + off);      off += (size_t)slots * JSP * MM * 4;
  float* pcn = (float*)(ws + off);      off += (size_t)slots * JSP * MM * 4;
  off = (off + 255) & ~(size_t)255;
  double* partials = (double*)(ws + off);  off += (size_t)slots * RG4 * JSP * 8;
  double* partials2 = (double*)(ws + off); off += (size_t)slots * CT * 8;

  int n1 = slots * RG4 * JSP;
  int n2 = slots * CT;

  hipLaunchKernelGGL(k_prep, dim3(TC * BB * 5 + slots), dim3(256), 0, stream,
                     pred, dsp, rv, tv, nts, dep, Ks, Kin, osz, ivl, warped);
  dim3 sgrid(slots, RGB4, JSP);
  hipLaunchKernelGGL(k_rnorm_p, sgrid, dim3(256), 0, stream, dsp, ivl, prn);
  hipLaunchKernelGGL(k_cnorm_p, sgrid, dim3(256), 0, stream, dsp, ivl, prn, pcn);
  hipLaunchKernelGGL(k_lc, dim3(slots, RGB4, JSP + 1), dim3(256), 0, stream,
                     dsp, ivl, prn, pcn, warped, niv, partials, partials2);
  hipLaunchKernelGGL(k_red, dim3(1), dim3(256), 0, stream, partials, n1, partials2, n2,
                     (float*)d_out);
}